// Round 1
// baseline (2019.234 us; speedup 1.0000x reference)
//
#include <hip/hip_runtime.h>
#include <hip/hip_bf16.h>

constexpr int NN  = 4096;       // n_node + 1 == batch
constexpr int T   = 32;
constexpr int D   = 64;
constexpr int DE  = 32;         // d_emb
constexpr int TD  = T * D;      // 2048
constexpr int KC  = 32;         // diffusion K-chunk

// ---------------- s[n] = sum_e emb[n,e] ----------------
__global__ __launch_bounds__(256) void k_s(const float* __restrict__ emb,
                                           float* __restrict__ s_g) {
    int n = blockIdx.x * 256 + threadIdx.x;
    const float4* e4 = (const float4*)(emb + n * DE);
    float s = 0.f;
#pragma unroll
    for (int i = 0; i < DE / 4; ++i) { float4 v = e4[i]; s += v.x + v.y + v.z + v.w; }
    s_g[n] = s;
}

// ---------------- invZ[n] = 1 / sum_m exp(elu(s_n - s_m)) ----------------
__global__ __launch_bounds__(256) void k_z(const float* __restrict__ s_g,
                                           float* __restrict__ invZ) {
    __shared__ float ss[NN];
    int tid = threadIdx.x;
    for (int i = tid; i < NN; i += 256) ss[i] = s_g[i];
    __syncthreads();
    int n = blockIdx.x * 256 + tid;
    float sn = ss[n];
    float z = 0.f;
    for (int m = 0; m < NN; ++m) {
        float x = sn - ss[m];
        float e = (x > 0.f) ? x : (__expf(x) - 1.f);
        z += __expf(e);
    }
    invZ[n] = 1.f / z;
}

// ---------------- Y[r,c] = sum_d X[r,d] * W[c,d] + b[c]  (torch Linear) ----------------
__global__ __launch_bounds__(256) void k_proj(const float* __restrict__ X,
                                              const float* __restrict__ W,
                                              const float* __restrict__ bias,
                                              float* __restrict__ Y) {
    __shared__ float xs[64 * 65];
    __shared__ float ws[64 * 65];
    __shared__ float bs[64];
    int tid  = threadIdx.x;
    int row0 = blockIdx.x * 64;
#pragma unroll
    for (int u = 0; u < 4; ++u) {
        int idx = tid + u * 256;            // 0..1023 float4s
        int r = idx >> 4, c4 = (idx & 15) << 2;
        float4 v = *(const float4*)&X[(row0 + r) * 64 + c4];
        xs[r * 65 + c4 + 0] = v.x; xs[r * 65 + c4 + 1] = v.y;
        xs[r * 65 + c4 + 2] = v.z; xs[r * 65 + c4 + 3] = v.w;
        float4 w = *(const float4*)&W[idx * 4];
        ws[r * 65 + c4 + 0] = w.x; ws[r * 65 + c4 + 1] = w.y;
        ws[r * 65 + c4 + 2] = w.z; ws[r * 65 + c4 + 3] = w.w;
    }
    if (tid < 64) bs[tid] = bias[tid];
    __syncthreads();
    int c = tid & 63, rg = tid >> 6;
#pragma unroll
    for (int rr = 0; rr < 16; ++rr) {
        int r = rg * 16 + rr;
        float acc = bs[c];
#pragma unroll
        for (int d = 0; d < 64; ++d) acc += xs[r * 65 + d] * ws[c * 65 + d];
        Y[(row0 + r) * 64 + c] = acc;
    }
}

// ---------------- Wnode[n] = sum_e emb[n,e] * We[e]  (two nodes per block) ----------------
__global__ __launch_bounds__(256) void k_wnode(const float* __restrict__ emb,
                                               const float* __restrict__ We,
                                               float* __restrict__ Wn) {
    __shared__ float es[2 * DE];
    int tid = threadIdx.x;
    int n0  = blockIdx.x * 2;
    if (tid < 2 * DE) es[tid] = emb[n0 * DE + tid];
    __syncthreads();
    float a[16] = {}, b[16] = {};
    for (int e = 0; e < DE; ++e) {
        float wa = es[e], wb = es[DE + e];
        const float* row = We + e * 4096;
#pragma unroll
        for (int i = 0; i < 16; ++i) {
            float t = row[i * 256 + tid];
            a[i] += wa * t; b[i] += wb * t;
        }
    }
#pragma unroll
    for (int i = 0; i < 16; ++i) {
        Wn[n0 * 4096 + i * 256 + tid]       = a[i];
        Wn[(n0 + 1) * 4096 + i * 256 + tid] = b[i];
    }
}

// ---------------- bnode[n,o] = sum_e emb[n,e] * be[e,o] ----------------
__global__ __launch_bounds__(256) void k_bnode(const float* __restrict__ emb,
                                               const float* __restrict__ be,
                                               float* __restrict__ bn) {
    int gid = blockIdx.x * 256 + threadIdx.x;   // 0..262143
    int n = gid >> 6, o = gid & 63;
    float acc = 0.f;
#pragma unroll
    for (int e = 0; e < DE; ++e) acc += emb[n * DE + e] * be[e * 64 + o];
    bn[gid] = acc;
}

// ---------------- diffusion GEMM: C[n,j] = sum_m A(n,m) * qp[m,j]  (A on the fly) -------
__global__ __launch_bounds__(256) void k_diff(const float* __restrict__ qp,
                                              const float* __restrict__ s_g,
                                              const float* __restrict__ invZ_g,
                                              float* __restrict__ out) {
    __shared__ float As[KC * 68];
    __shared__ float Qs[KC * 68];
    const int tid = threadIdx.x;
    const int bn0 = blockIdx.x * 64;   // node tile
    const int bj0 = blockIdx.y * 64;   // (t,d) tile
    const int nn  = tid & 63;
    const float sn = s_g[bn0 + nn];
    const float rz = invZ_g[bn0 + nn];
    const int kgrp = tid >> 6;          // 0..3
    const int tj = tid & 15, tn = tid >> 4;
    float acc[4][4] = {};
    for (int km0 = 0; km0 < NN; km0 += KC) {
        // stage Q chunk [KC x 64]
#pragma unroll
        for (int u = 0; u < 2; ++u) {
            int idx = tid + u * 256;       // 0..511 float4s
            int kk = idx >> 4, j4 = (idx & 15) << 2;
            float4 v = *(const float4*)&qp[(km0 + kk) * TD + bj0 + j4];
            *(float4*)&Qs[kk * 68 + j4] = v;
        }
        // generate A chunk [KC x 64] (transposed: As[kk][nn])
#pragma unroll
        for (int i = 0; i < 8; ++i) {
            int kk = kgrp * 8 + i;
            int m  = km0 + kk;
            float x = sn - s_g[m];
            float e = (x > 0.f) ? x : (__expf(x) - 1.f);
            float w = __expf(e) * rz + ((m == bn0 + nn) ? 1.f : 0.f);
            As[kk * 68 + nn] = w;
        }
        __syncthreads();
#pragma unroll 8
        for (int kk = 0; kk < KC; ++kk) {
            float4 a  = *(const float4*)&As[kk * 68 + (tn << 2)];
            float4 qv = *(const float4*)&Qs[kk * 68 + (tj << 2)];
            acc[0][0] += a.x * qv.x; acc[0][1] += a.x * qv.y; acc[0][2] += a.x * qv.z; acc[0][3] += a.x * qv.w;
            acc[1][0] += a.y * qv.x; acc[1][1] += a.y * qv.y; acc[1][2] += a.y * qv.z; acc[1][3] += a.y * qv.w;
            acc[2][0] += a.z * qv.x; acc[2][1] += a.z * qv.y; acc[2][2] += a.z * qv.z; acc[2][3] += a.z * qv.w;
            acc[3][0] += a.w * qv.x; acc[3][1] += a.w * qv.y; acc[3][2] += a.w * qv.z; acc[3][3] += a.w * qv.w;
        }
        __syncthreads();
    }
#pragma unroll
    for (int i = 0; i < 4; ++i) {
        float4 v = make_float4(acc[i][0], acc[i][1], acc[i][2], acc[i][3]);
        *(float4*)&out[(bn0 + (tn << 2) + i) * TD + bj0 + (tj << 2)] = v;
    }
}

// ---------------- q2[n,t,o] = sum_d qdif[n,t,d] * Wn[n,d,o] + bn[n,o] ----------------
__global__ __launch_bounds__(256) void k_nodemm(const float* __restrict__ qdif,
                                                const float* __restrict__ Wn,
                                                const float* __restrict__ bn,
                                                float* __restrict__ q2) {
    __shared__ float xs[T * 65];
    __shared__ float ws[64 * 65];
    __shared__ float bs[64];
    int tid = threadIdx.x;
    int n   = blockIdx.x;
#pragma unroll
    for (int u = 0; u < 2; ++u) {
        int idx = tid + u * 256; int r = idx >> 4, c4 = (idx & 15) << 2;
        float4 v = *(const float4*)&qdif[n * TD + r * 64 + c4];
        xs[r * 65 + c4 + 0] = v.x; xs[r * 65 + c4 + 1] = v.y;
        xs[r * 65 + c4 + 2] = v.z; xs[r * 65 + c4 + 3] = v.w;
    }
#pragma unroll
    for (int u = 0; u < 4; ++u) {
        int idx = tid + u * 256; int r = idx >> 4, c4 = (idx & 15) << 2;
        float4 v = *(const float4*)&Wn[n * 4096 + idx * 4];
        ws[r * 65 + c4 + 0] = v.x; ws[r * 65 + c4 + 1] = v.y;
        ws[r * 65 + c4 + 2] = v.z; ws[r * 65 + c4 + 3] = v.w;
    }
    if (tid < 64) bs[tid] = bn[n * 64 + tid];
    __syncthreads();
    int o = tid & 63, rg = tid >> 6;
#pragma unroll
    for (int rr = 0; rr < 8; ++rr) {
        int r = rg * 8 + rr;
        float acc = bs[o];
#pragma unroll
        for (int d = 0; d < 64; ++d) acc += xs[r * 65 + d] * ws[d * 65 + o];
        q2[n * TD + r * 64 + o] = acc;
    }
}

// ---------------- per-batch 8-head attention + Wo epilogue ----------------
__global__ __launch_bounds__(256) void k_attn(const float* __restrict__ q2,
                                              const float* __restrict__ kp,
                                              const float* __restrict__ vp,
                                              const float* __restrict__ Wo,
                                              const float* __restrict__ bo,
                                              float* __restrict__ out) {
    __shared__ float qs[T * 65], ks[T * 65], vs[T * 65], att[T * 65];
    __shared__ float wos[64 * 65];
    __shared__ float bos[64];
    int tid = threadIdx.x;
    int b   = blockIdx.x;
#pragma unroll
    for (int u = 0; u < 2; ++u) {
        int idx = tid + u * 256; int r = idx >> 4, c4 = (idx & 15) << 2;
        float4 v;
        v = *(const float4*)&q2[b * TD + r * 64 + c4];
        qs[r * 65 + c4 + 0] = v.x; qs[r * 65 + c4 + 1] = v.y; qs[r * 65 + c4 + 2] = v.z; qs[r * 65 + c4 + 3] = v.w;
        v = *(const float4*)&kp[b * TD + r * 64 + c4];
        ks[r * 65 + c4 + 0] = v.x; ks[r * 65 + c4 + 1] = v.y; ks[r * 65 + c4 + 2] = v.z; ks[r * 65 + c4 + 3] = v.w;
        v = *(const float4*)&vp[b * TD + r * 64 + c4];
        vs[r * 65 + c4 + 0] = v.x; vs[r * 65 + c4 + 1] = v.y; vs[r * 65 + c4 + 2] = v.z; vs[r * 65 + c4 + 3] = v.w;
    }
#pragma unroll
    for (int u = 0; u < 4; ++u) {
        int idx = tid + u * 256; int r = idx >> 4, c4 = (idx & 15) << 2;
        float4 v = *(const float4*)&Wo[idx * 4];
        wos[r * 65 + c4 + 0] = v.x; wos[r * 65 + c4 + 1] = v.y;
        wos[r * 65 + c4 + 2] = v.z; wos[r * 65 + c4 + 3] = v.w;
    }
    if (tid < 64) bos[tid] = bo[tid];
    __syncthreads();
    int h = tid >> 5, tq = tid & 31;
    float qr[8];
#pragma unroll
    for (int d = 0; d < 8; ++d) qr[d] = qs[tq * 65 + h * 8 + d];
    float sc[32]; float mx = -1e30f;
#pragma unroll
    for (int s_ = 0; s_ < 32; ++s_) {
        float dot = 0.f;
#pragma unroll
        for (int d = 0; d < 8; ++d) dot += qr[d] * ks[s_ * 65 + h * 8 + d];
        dot *= 0.35355339059327373f;   // 1/sqrt(8)
        sc[s_] = dot; mx = fmaxf(mx, dot);
    }
    float sum = 0.f;
#pragma unroll
    for (int s_ = 0; s_ < 32; ++s_) { float e = __expf(sc[s_] - mx); sc[s_] = e; sum += e; }
    float inv = 1.f / sum;
#pragma unroll
    for (int d = 0; d < 8; ++d) {
        float o = 0.f;
#pragma unroll
        for (int s_ = 0; s_ < 32; ++s_) o += sc[s_] * vs[s_ * 65 + h * 8 + d];
        att[tq * 65 + h * 8 + d] = o * inv;
    }
    __syncthreads();
    int c = tid & 63, rg = tid >> 6;
#pragma unroll
    for (int rr = 0; rr < 8; ++rr) {
        int r = rg * 8 + rr;
        float acc = bos[c];
#pragma unroll
        for (int d = 0; d < 64; ++d) acc += att[r * 65 + d] * wos[c * 65 + d];
        out[b * TD + r * 64 + c] = acc;
    }
}

extern "C" void kernel_launch(void* const* d_in, const int* in_sizes, int n_in,
                              void* d_out, int out_size, void* d_ws, size_t ws_size,
                              hipStream_t stream) {
    const float* q   = (const float*)d_in[0];
    const float* k   = (const float*)d_in[1];
    const float* v   = (const float*)d_in[2];
    const float* emb = (const float*)d_in[3];
    const float* We  = (const float*)d_in[4];
    const float* be  = (const float*)d_in[5];
    const float* Wq  = (const float*)d_in[6];
    const float* bq  = (const float*)d_in[7];
    const float* Wk  = (const float*)d_in[8];
    const float* bk  = (const float*)d_in[9];
    const float* Wv  = (const float*)d_in[10];
    const float* bv  = (const float*)d_in[11];
    const float* Wo  = (const float*)d_in[12];
    const float* bo  = (const float*)d_in[13];

    float* ws  = (float*)d_ws;
    float* qp  = ws;                    //  8,388,608 floats
    float* kp  = ws + 8388608;
    float* vp  = ws + 16777216;
    float* Wn  = ws + 25165824;         // 16,777,216 floats
    float* bn  = ws + 41943040;         //    262,144
    float* s_g = ws + 42205184;         //      4,096
    float* iz  = ws + 42209280;         //      4,096  (total 161 MB)
    float* outp = (float*)d_out;
    float* q2   = qp;                    // qp dead after k_diff -> reuse

    k_s    <<<16, 256, 0, stream>>>(emb, s_g);
    k_z    <<<16, 256, 0, stream>>>(s_g, iz);
    k_proj <<<2048, 256, 0, stream>>>(q, Wq, bq, qp);
    k_proj <<<2048, 256, 0, stream>>>(k, Wk, bk, kp);
    k_proj <<<2048, 256, 0, stream>>>(v, Wv, bv, vp);
    k_wnode<<<2048, 256, 0, stream>>>(emb, We, Wn);
    k_bnode<<<1024, 256, 0, stream>>>(emb, be, bn);
    // diffusion: writes qdif into d_out (scratch), fully overwritten later
    k_diff  <<<dim3(64, 32), 256, 0, stream>>>(qp, s_g, iz, outp);
    k_nodemm<<<4096, 256, 0, stream>>>(outp, Wn, bn, q2);
    k_attn  <<<4096, 256, 0, stream>>>(q2, kp, vp, Wo, bo, outp);
}

// Round 2
// 369.437 us; speedup vs baseline: 5.4657x; 5.4657x over previous
//
#include <hip/hip_runtime.h>
#include <hip/hip_bf16.h>

constexpr int NN  = 4096;       // n_node + 1 == batch
constexpr int DE  = 32;         // d_emb
constexpr int TD  = 2048;       // T*D

typedef __attribute__((ext_vector_type(8))) short short8;
typedef __attribute__((ext_vector_type(4))) float f32x4;

#define MFMA16(a, b, c) __builtin_amdgcn_mfma_f32_16x16x32_bf16(a, b, c, 0, 0, 0)

__device__ inline ushort f2b(float x) {
    union { float f; unsigned u; } c; c.f = x;
    unsigned r = (c.u + 0x7FFF + ((c.u >> 16) & 1)) >> 16;
    return (ushort)r;
}

__device__ inline short8 pack8(float4 a, float4 b) {
    short8 v;
    v[0] = (short)f2b(a.x); v[1] = (short)f2b(a.y); v[2] = (short)f2b(a.z); v[3] = (short)f2b(a.w);
    v[4] = (short)f2b(b.x); v[5] = (short)f2b(b.y); v[6] = (short)f2b(b.z); v[7] = (short)f2b(b.w);
    return v;
}

// ---------------- s[n] = sum_e emb[n,e] ----------------
__global__ __launch_bounds__(256) void k_s(const float* __restrict__ emb,
                                           float* __restrict__ s_g) {
    int n = blockIdx.x * 256 + threadIdx.x;
    const float4* e4 = (const float4*)(emb + n * DE);
    float s = 0.f;
#pragma unroll
    for (int i = 0; i < DE / 4; ++i) { float4 v = e4[i]; s += v.x + v.y + v.z + v.w; }
    s_g[n] = s;
}

// ---------------- invZ[n] = 1 / sum_m exp(elu(s_n - s_m)) ----------------
__global__ __launch_bounds__(256) void k_z(const float* __restrict__ s_g,
                                           float* __restrict__ invZ) {
    __shared__ float ss[NN];
    int tid = threadIdx.x;
    for (int i = tid; i < NN; i += 256) ss[i] = s_g[i];
    __syncthreads();
    int n = blockIdx.x * 256 + tid;
    float sn = ss[n];
    float z = 0.f;
    for (int m = 0; m < NN; ++m) {
        float x = sn - ss[m];
        float e = (x > 0.f) ? x : (__expf(x) - 1.f);
        z += __expf(e);
    }
    invZ[n] = 1.f / z;
}

// ---------------- Abf[n,m] bf16 = softmax(elu(sn-sm)) + I ----------------
__global__ __launch_bounds__(256) void k_abf(const float* __restrict__ s_g,
                                             const float* __restrict__ iz,
                                             ushort* __restrict__ Abf) {
    int gid = blockIdx.x * 256 + threadIdx.x;      // 4,194,304 threads
    int n = gid >> 10, m4 = (gid & 1023) * 4;
    float sn = s_g[n], rz = iz[n];
    float4 sm = *(const float4*)&s_g[m4];
    float w[4]; float smv[4] = {sm.x, sm.y, sm.z, sm.w};
#pragma unroll
    for (int i = 0; i < 4; ++i) {
        float x = sn - smv[i];
        float e = (x > 0.f) ? x : (__expf(x) - 1.f);
        w[i] = __expf(e) * rz + ((m4 + i == n) ? 1.f : 0.f);
    }
    ushort4 o; o.x = f2b(w[0]); o.y = f2b(w[1]); o.z = f2b(w[2]); o.w = f2b(w[3]);
    *(ushort4*)&Abf[(size_t)n * 4096 + m4] = o;
}

// ---------------- MFMA projection: Y[r,c] = sum_k X[r,k] W[c,k] + b[c] ----------------
__global__ __launch_bounds__(256) void k_projm(const float* __restrict__ X,
                                               const float* __restrict__ W,
                                               const float* __restrict__ bias,
                                               float* __restrict__ Y) {
    int tid = threadIdx.x, lane = tid & 63, wid = tid >> 6;
    int r0 = blockIdx.x * 256 + wid * 64;
    int l15 = lane & 15, kb = lane >> 4;
    f32x4 acc[4][4] = {};
#pragma unroll
    for (int ks = 0; ks < 2; ++ks) {
        short8 af[4], bf[4];
#pragma unroll
        for (int f = 0; f < 4; ++f) {
            const float* ap = X + (size_t)(r0 + f * 16 + l15) * 64 + ks * 32 + kb * 8;
            float4 x0 = *(const float4*)ap;
            float4 x1 = *(const float4*)(ap + 4);
            af[f] = pack8(x0, x1);
            const float* bp = W + (size_t)(f * 16 + l15) * 64 + ks * 32 + kb * 8;
            float4 w0 = *(const float4*)bp;
            float4 w1 = *(const float4*)(bp + 4);
            bf[f] = pack8(w0, w1);
        }
#pragma unroll
        for (int i = 0; i < 4; ++i)
#pragma unroll
            for (int j = 0; j < 4; ++j)
                acc[i][j] = MFMA16(af[i], bf[j], acc[i][j]);
    }
    float bcol[4];
#pragma unroll
    for (int j = 0; j < 4; ++j) bcol[j] = bias[j * 16 + l15];
#pragma unroll
    for (int i = 0; i < 4; ++i)
#pragma unroll
        for (int j = 0; j < 4; ++j)
#pragma unroll
            for (int r = 0; r < 4; ++r)
                Y[(size_t)(r0 + i * 16 + kb * 4 + r) * 64 + j * 16 + l15] = acc[i][j][r] + bcol[j];
}

// ---------------- transpose qp [4096][2048] f32 -> QbfT [2048][4096] bf16 ----------------
__global__ __launch_bounds__(256) void k_qbf(const float* __restrict__ qp,
                                             ushort* __restrict__ qt) {
    __shared__ float t[64][65];
    int m0 = blockIdx.x * 64, j0 = blockIdx.y * 64;
    int tid = threadIdx.x;
#pragma unroll
    for (int u = 0; u < 4; ++u) {
        int idx = tid + u * 256; int r = idx >> 4, c4 = (idx & 15) * 4;
        float4 v = *(const float4*)&qp[(size_t)(m0 + r) * 2048 + j0 + c4];
        t[r][c4] = v.x; t[r][c4 + 1] = v.y; t[r][c4 + 2] = v.z; t[r][c4 + 3] = v.w;
    }
    __syncthreads();
#pragma unroll
    for (int u = 0; u < 4; ++u) {
        int idx = tid + u * 256; int r = idx >> 4, c4 = (idx & 15) * 4;
        ushort4 o;
        o.x = f2b(t[c4][r]); o.y = f2b(t[c4 + 1][r]);
        o.z = f2b(t[c4 + 2][r]); o.w = f2b(t[c4 + 3][r]);
        *(ushort4*)&qt[(size_t)(j0 + r) * 4096 + m0 + c4] = o;
    }
}

// ---------------- diffusion MFMA GEMM: qdif[n,j] = sum_m Abf[n,m] QbfT[j,m] ----------------
__global__ __launch_bounds__(256) void k_diffm(const ushort* __restrict__ Abf,
                                               const ushort* __restrict__ QbfT,
                                               ushort* __restrict__ qdifb) {
    __shared__ ushort As[128 * 40];
    __shared__ ushort Qs[128 * 40];
    const int tid = threadIdx.x;
    const int lane = tid & 63, wid = tid >> 6;
    const int n0 = blockIdx.x * 128, j0 = blockIdx.y * 128;
    const int wm = (wid >> 1) * 64, wn = (wid & 1) * 64;
    const int sr = tid >> 2, sc = (tid & 3) * 8;
    const ushort* ag = Abf + (size_t)(n0 + sr) * 4096 + sc;
    const ushort* qg = QbfT + (size_t)(j0 + sr) * 4096 + sc;
    const int l15 = lane & 15, kb = lane >> 4;
    const int aoff = (wm + l15) * 40 + kb * 8;
    const int boff = (wn + l15) * 40 + kb * 8;
    f32x4 acc[4][4] = {};
    for (int km = 0; km < 4096; km += 32) {
        uint4 a0 = *(const uint4*)(ag + km);
        uint4 a1 = *(const uint4*)(ag + km + (size_t)64 * 4096);
        uint4 q0 = *(const uint4*)(qg + km);
        uint4 q1 = *(const uint4*)(qg + km + (size_t)64 * 4096);
        __syncthreads();
        *(uint4*)&As[sr * 40 + sc] = a0;
        *(uint4*)&As[(sr + 64) * 40 + sc] = a1;
        *(uint4*)&Qs[sr * 40 + sc] = q0;
        *(uint4*)&Qs[(sr + 64) * 40 + sc] = q1;
        __syncthreads();
        short8 af[4], bf[4];
#pragma unroll
        for (int f = 0; f < 4; ++f) {
            af[f] = *(const short8*)&As[aoff + f * 16 * 40];
            bf[f] = *(const short8*)&Qs[boff + f * 16 * 40];
        }
#pragma unroll
        for (int i = 0; i < 4; ++i)
#pragma unroll
            for (int j = 0; j < 4; ++j)
                acc[i][j] = MFMA16(af[i], bf[j], acc[i][j]);
    }
#pragma unroll
    for (int i = 0; i < 4; ++i)
#pragma unroll
        for (int j = 0; j < 4; ++j)
#pragma unroll
            for (int r = 0; r < 4; ++r)
                qdifb[(size_t)(n0 + wm + i * 16 + kb * 4 + r) * 2048 + j0 + wn + j * 16 + l15] =
                    f2b(acc[i][j][r]);
}

// ---------------- transpose We: WeT[e][o][d] = We[e][d][o] ----------------
__global__ __launch_bounds__(256) void k_wet(const float* __restrict__ We,
                                             float* __restrict__ WeT) {
    __shared__ float t[64][65];
    int e = blockIdx.x, tid = threadIdx.x;
#pragma unroll
    for (int u = 0; u < 4; ++u) {
        int idx = tid + u * 256; int r = idx >> 4, c4 = (idx & 15) * 4;
        float4 v = *(const float4*)&We[(size_t)e * 4096 + r * 64 + c4];
        t[r][c4] = v.x; t[r][c4 + 1] = v.y; t[r][c4 + 2] = v.z; t[r][c4 + 3] = v.w;
    }
    __syncthreads();
#pragma unroll
    for (int u = 0; u < 4; ++u) {
        int idx = tid + u * 256; int r = idx >> 4, c4 = (idx & 15) * 4;
        float4 o;
        o.x = t[c4][r]; o.y = t[c4 + 1][r]; o.z = t[c4 + 2][r]; o.w = t[c4 + 3][r];
        *(float4*)&WeT[(size_t)e * 4096 + r * 64 + c4] = o;
    }
}

// ---------------- WnT[n][o*64+d] bf16 = sum_e emb[n,e] WeT[e][o*64+d] (4 nodes/block) ----
__global__ __launch_bounds__(256) void k_wnode(const float* __restrict__ emb,
                                               const float* __restrict__ WeT,
                                               ushort* __restrict__ WnT) {
    __shared__ float es[4 * DE];
    int tid = threadIdx.x;
    int n0 = blockIdx.x * 4;
    if (tid < 4 * DE) es[tid] = emb[n0 * DE + tid];
    __syncthreads();
    float a0[16] = {}, a1[16] = {}, a2[16] = {}, a3[16] = {};
    for (int e = 0; e < DE; ++e) {
        float w0 = es[e], w1 = es[DE + e], w2 = es[2 * DE + e], w3 = es[3 * DE + e];
        const float* row = WeT + (size_t)e * 4096;
#pragma unroll
        for (int i = 0; i < 16; ++i) {
            float t = row[i * 256 + tid];
            a0[i] += w0 * t; a1[i] += w1 * t; a2[i] += w2 * t; a3[i] += w3 * t;
        }
    }
#pragma unroll
    for (int i = 0; i < 16; ++i) {
        WnT[(size_t)n0 * 4096 + i * 256 + tid]       = f2b(a0[i]);
        WnT[(size_t)(n0 + 1) * 4096 + i * 256 + tid] = f2b(a1[i]);
        WnT[(size_t)(n0 + 2) * 4096 + i * 256 + tid] = f2b(a2[i]);
        WnT[(size_t)(n0 + 3) * 4096 + i * 256 + tid] = f2b(a3[i]);
    }
}

// ---------------- bnode[n,o] = sum_e emb[n,e] * be[e,o] ----------------
__global__ __launch_bounds__(256) void k_bnode(const float* __restrict__ emb,
                                               const float* __restrict__ be,
                                               float* __restrict__ bn) {
    int gid = blockIdx.x * 256 + threadIdx.x;
    int n = gid >> 6, o = gid & 63;
    float acc = 0.f;
#pragma unroll
    for (int e = 0; e < DE; ++e) acc += emb[n * DE + e] * be[e * 64 + o];
    bn[gid] = acc;
}

// ---------------- per-node MFMA: q2[n] = qdif[n](32x64) @ WnT[n]^T + bn[n] ----------------
__global__ __launch_bounds__(256) void k_nodemm(const ushort* __restrict__ qd,
                                                const ushort* __restrict__ WnT,
                                                const float* __restrict__ bn,
                                                float* __restrict__ q2) {
    int n = blockIdx.x;
    int tid = threadIdx.x, lane = tid & 63, wid = tid >> 6;
    int l15 = lane & 15, kb = lane >> 4;
    int fm = wid & 1;
    int fn0 = (wid >> 1) * 2;
    f32x4 acc[2] = {};
    const ushort* A = qd + (size_t)n * 2048;
    const ushort* B = WnT + (size_t)n * 4096;
#pragma unroll
    for (int ks = 0; ks < 2; ++ks) {
        short8 af = *(const short8*)(A + (fm * 16 + l15) * 64 + ks * 32 + kb * 8);
#pragma unroll
        for (int j = 0; j < 2; ++j) {
            short8 bf = *(const short8*)(B + (size_t)((fn0 + j) * 16 + l15) * 64 + ks * 32 + kb * 8);
            acc[j] = MFMA16(af, bf, acc[j]);
        }
    }
#pragma unroll
    for (int j = 0; j < 2; ++j) {
        int col = (fn0 + j) * 16 + l15;
        float bb = bn[n * 64 + col];
#pragma unroll
        for (int r = 0; r < 4; ++r) {
            int row = fm * 16 + kb * 4 + r;
            q2[(size_t)n * 2048 + row * 64 + col] = acc[j][r] + bb;
        }
    }
}

// ---------------- per-batch 8-head attention + Wo epilogue ----------------
__global__ __launch_bounds__(256) void k_attn(const float* __restrict__ q2,
                                              const float* __restrict__ kp,
                                              const float* __restrict__ vp,
                                              const float* __restrict__ Wo,
                                              const float* __restrict__ bo,
                                              float* __restrict__ out) {
    __shared__ float qs[32 * 68], ks[32 * 68], vs[32 * 68], att[32 * 68];
    __shared__ float wos[64 * 68];
    __shared__ float bos[64];
    int tid = threadIdx.x;
    int b = blockIdx.x;
    {
        int r = tid >> 3, c8 = (tid & 7) * 8;
        const float* s0 = q2 + (size_t)b * TD + r * 64 + c8;
        const float* s1 = kp + (size_t)b * TD + r * 64 + c8;
        const float* s2 = vp + (size_t)b * TD + r * 64 + c8;
        *(float4*)&qs[r * 68 + c8]     = *(const float4*)s0;
        *(float4*)&qs[r * 68 + c8 + 4] = *(const float4*)(s0 + 4);
        *(float4*)&ks[r * 68 + c8]     = *(const float4*)s1;
        *(float4*)&ks[r * 68 + c8 + 4] = *(const float4*)(s1 + 4);
        *(float4*)&vs[r * 68 + c8]     = *(const float4*)s2;
        *(float4*)&vs[r * 68 + c8 + 4] = *(const float4*)(s2 + 4);
    }
#pragma unroll
    for (int u = 0; u < 4; ++u) {
        int idx = tid + u * 256; int r = idx >> 4, c4 = (idx & 15) * 4;
        *(float4*)&wos[r * 68 + c4] = *(const float4*)&Wo[idx * 4];
    }
    if (tid < 64) bos[tid] = bo[tid];
    __syncthreads();
    int h = tid >> 5, tq = tid & 31;
    float4 q0 = *(const float4*)&qs[tq * 68 + h * 8];
    float4 q1 = *(const float4*)&qs[tq * 68 + h * 8 + 4];
    float sc[32]; float mx = -1e30f;
#pragma unroll
    for (int s_ = 0; s_ < 32; ++s_) {
        float4 k0 = *(const float4*)&ks[s_ * 68 + h * 8];
        float4 k1 = *(const float4*)&ks[s_ * 68 + h * 8 + 4];
        float dot = q0.x * k0.x + q0.y * k0.y + q0.z * k0.z + q0.w * k0.w
                  + q1.x * k1.x + q1.y * k1.y + q1.z * k1.z + q1.w * k1.w;
        dot *= 0.35355339059327373f;
        sc[s_] = dot; mx = fmaxf(mx, dot);
    }
    float sum = 0.f;
#pragma unroll
    for (int s_ = 0; s_ < 32; ++s_) { float e = __expf(sc[s_] - mx); sc[s_] = e; sum += e; }
    float inv = 1.f / sum;
    float oa[8] = {};
#pragma unroll
    for (int s_ = 0; s_ < 32; ++s_) {
        float w = sc[s_];
        float4 v0 = *(const float4*)&vs[s_ * 68 + h * 8];
        float4 v1 = *(const float4*)&vs[s_ * 68 + h * 8 + 4];
        oa[0] += w * v0.x; oa[1] += w * v0.y; oa[2] += w * v0.z; oa[3] += w * v0.w;
        oa[4] += w * v1.x; oa[5] += w * v1.y; oa[6] += w * v1.z; oa[7] += w * v1.w;
    }
    float4 w0 = make_float4(oa[0] * inv, oa[1] * inv, oa[2] * inv, oa[3] * inv);
    float4 w1 = make_float4(oa[4] * inv, oa[5] * inv, oa[6] * inv, oa[7] * inv);
    *(float4*)&att[tq * 68 + h * 8]     = w0;
    *(float4*)&att[tq * 68 + h * 8 + 4] = w1;
    __syncthreads();
    int rp = tid & 15, g = tid >> 4;
    float a0[4] = {}, a1[4] = {};
#pragma unroll
    for (int d4 = 0; d4 < 16; ++d4) {
        float4 x0 = *(const float4*)&att[rp * 68 + d4 * 4];
        float4 x1 = *(const float4*)&att[(rp + 16) * 68 + d4 * 4];
#pragma unroll
        for (int i = 0; i < 4; ++i) {
            float4 w = *(const float4*)&wos[(g * 4 + i) * 68 + d4 * 4];
            a0[i] += x0.x * w.x + x0.y * w.y + x0.z * w.z + x0.w * w.w;
            a1[i] += x1.x * w.x + x1.y * w.y + x1.z * w.z + x1.w * w.w;
        }
    }
    float4 r0 = make_float4(a0[0] + bos[g * 4], a0[1] + bos[g * 4 + 1],
                            a0[2] + bos[g * 4 + 2], a0[3] + bos[g * 4 + 3]);
    float4 r1 = make_float4(a1[0] + bos[g * 4], a1[1] + bos[g * 4 + 1],
                            a1[2] + bos[g * 4 + 2], a1[3] + bos[g * 4 + 3]);
    *(float4*)&out[(size_t)b * TD + rp * 64 + g * 4]        = r0;
    *(float4*)&out[(size_t)b * TD + (rp + 16) * 64 + g * 4] = r1;
}

extern "C" void kernel_launch(void* const* d_in, const int* in_sizes, int n_in,
                              void* d_out, int out_size, void* d_ws, size_t ws_size,
                              hipStream_t stream) {
    const float* q   = (const float*)d_in[0];
    const float* k   = (const float*)d_in[1];
    const float* v   = (const float*)d_in[2];
    const float* emb = (const float*)d_in[3];
    const float* We  = (const float*)d_in[4];
    const float* be  = (const float*)d_in[5];
    const float* Wq  = (const float*)d_in[6];
    const float* bq  = (const float*)d_in[7];
    const float* Wk  = (const float*)d_in[8];
    const float* bk  = (const float*)d_in[9];
    const float* Wv  = (const float*)d_in[10];
    const float* bv  = (const float*)d_in[11];
    const float* Wo  = (const float*)d_in[12];
    const float* bo  = (const float*)d_in[13];

    float* ws = (float*)d_ws;
    float*  qp    = ws;                                   // [0, 8388608)  (q2 later)
    float*  kp    = ws + 8388608;                         // [8388608, 16777216)
    float*  vp    = ws + 16777216;                        // [16777216, 25165824)
    ushort* QbfT  = (ushort*)(ws + 25165824);             // 16 MB  (dead after k_diffm)
    ushort* WnT   = (ushort*)(ws + 25165824);             // 32 MB  (written after k_diffm)
    ushort* qdifb = (ushort*)(ws + 33554432);             // 16 MB
    float*  bn    = ws + 37748736;                        // 1 MB
    float*  s_g   = ws + 38010880;
    float*  iz    = ws + 38014976;
    float*  WeT   = ws + 38019072;                        // 512 KB  (end = 152.6 MB)
    ushort* Abf   = (ushort*)d_out;                       // 32 MB scratch in d_out
    float*  q2    = qp;
    float*  outp  = (float*)d_out;

    k_s    <<<16, 256, 0, stream>>>(emb, s_g);
    k_z    <<<16, 256, 0, stream>>>(s_g, iz);
    k_wet  <<<32, 256, 0, stream>>>(We, WeT);
    k_projm<<<512, 256, 0, stream>>>(q, Wq, bq, qp);
    k_projm<<<512, 256, 0, stream>>>(k, Wk, bk, kp);
    k_projm<<<512, 256, 0, stream>>>(v, Wv, bv, vp);
    k_abf  <<<16384, 256, 0, stream>>>(s_g, iz, Abf);
    k_qbf  <<<dim3(64, 32), 256, 0, stream>>>(qp, QbfT);
    k_diffm<<<dim3(32, 16), 256, 0, stream>>>(Abf, QbfT, qdifb);
    // QbfT dead from here; WnT may overwrite its region
    k_wnode<<<1024, 256, 0, stream>>>(emb, WeT, WnT);
    k_bnode<<<1024, 256, 0, stream>>>(emb, be, bn);
    k_nodemm<<<4096, 256, 0, stream>>>(qdifb, WnT, bn, q2);
    k_attn <<<4096, 256, 0, stream>>>(q2, kp, vp, Wo, bo, outp);
}

// Round 3
// 223.124 us; speedup vs baseline: 9.0498x; 1.6558x over previous
//
#include <hip/hip_runtime.h>
#include <hip/hip_bf16.h>

constexpr int NN  = 4096;       // n_node + 1 == batch
constexpr int DE  = 32;         // d_emb
constexpr int TD  = 2048;       // T*D

typedef __attribute__((ext_vector_type(8))) short short8;
typedef __attribute__((ext_vector_type(4))) float f32x4;

#define MFMA16(a, b, c) __builtin_amdgcn_mfma_f32_16x16x32_bf16(a, b, c, 0, 0, 0)

__device__ inline ushort f2b(float x) {
    union { float f; unsigned u; } c; c.f = x;
    unsigned r = (c.u + 0x7FFF + ((c.u >> 16) & 1)) >> 16;
    return (ushort)r;
}

__device__ inline short8 pack8(float4 a, float4 b) {
    short8 v;
    v[0] = (short)f2b(a.x); v[1] = (short)f2b(a.y); v[2] = (short)f2b(a.z); v[3] = (short)f2b(a.w);
    v[4] = (short)f2b(b.x); v[5] = (short)f2b(b.y); v[6] = (short)f2b(b.z); v[7] = (short)f2b(b.w);
    return v;
}

// ---------------- s[n] = sum_e emb[n,e] ----------------
__global__ __launch_bounds__(256) void k_s(const float* __restrict__ emb,
                                           float* __restrict__ s_g) {
    int n = blockIdx.x * 256 + threadIdx.x;
    const float4* e4 = (const float4*)(emb + n * DE);
    float s = 0.f;
#pragma unroll
    for (int i = 0; i < DE / 4; ++i) { float4 v = e4[i]; s += v.x + v.y + v.z + v.w; }
    s_g[n] = s;
}

// ---------------- rank[n] = #{m: (s_m,m) < (s_n,n)}; perm[rank]=n ----------------
__global__ __launch_bounds__(256) void k_rank(const float* __restrict__ s_g,
                                              int* __restrict__ perm) {
    __shared__ float ss[NN];
    int tid = threadIdx.x;
    for (int i = tid; i < NN; i += 256) ss[i] = s_g[i];
    __syncthreads();
    int g = tid >> 5, l = tid & 31;
    int n = blockIdx.x * 8 + g;
    float sn = ss[n];
    int cnt = 0;
    for (int j2 = 0; j2 < 128; ++j2) {
        int m = j2 * 32 + l;                 // bank = l -> conflict-free
        float sm = ss[m];
        cnt += (sm < sn) || (sm == sn && m < n);
    }
    for (int off = 16; off; off >>= 1) cnt += __shfl_down(cnt, off, 32);
    if (l == 0) perm[cnt] = n;
}

// ---------------- chunk sums: Cj[c][j][k] = sum_{i in chunk c} b^k * q[perm[i]][j] ------
__global__ __launch_bounds__(256) void k_csum(const float* __restrict__ qp,
                                              const float* __restrict__ s_g,
                                              const int* __restrict__ perm,
                                              float* __restrict__ Cj,
                                              float* __restrict__ Cb) {
    __shared__ int ns[64];
    __shared__ float bs[64];
    int bx = blockIdx.x, by = blockIdx.y, tid = threadIdx.x;
    if (tid < 64) {
        int n = perm[bx * 64 + tid];
        ns[tid] = n;
        bs[tid] = __expf(-s_g[n]);
    }
    __syncthreads();
    int j = by * 256 + tid;
    float run[8] = {};
    for (int ii = 0; ii < 64; ++ii) {
        float qv = qp[(size_t)ns[ii] * 2048 + j];
        float b = bs[ii], t = qv;
#pragma unroll
        for (int k2 = 0; k2 < 8; ++k2) { run[k2] += t; t *= b; }
    }
    float* cp = Cj + ((size_t)bx * 2048 + j) * 8;
    *(float4*)cp       = make_float4(run[0], run[1], run[2], run[3]);
    *(float4*)(cp + 4) = make_float4(run[4], run[5], run[6], run[7]);
    if (by == 0 && tid < 64) {
        float b = bs[tid], bk = 1.f;
#pragma unroll
        for (int k2 = 0; k2 < 8; ++k2) {
            float v = bk;
            for (int off = 32; off; off >>= 1) v += __shfl_down(v, off, 64);
            if (tid == 0) Cb[bx * 8 + k2] = v;
            bk *= b;
        }
    }
}

// ---------------- combine: qdif[n,j] = invZ*(a*pre1 + sum_k g_k (T_k - pre_k)) + q -------
__global__ __launch_bounds__(256) void k_comb(const float* __restrict__ qp,
                                              const float* __restrict__ s_g,
                                              const int* __restrict__ perm,
                                              const float* __restrict__ Cj,
                                              const float* __restrict__ Cb,
                                              ushort* __restrict__ qdifb) {
    __shared__ int ns[64];
    __shared__ float sa[64], sb[64];
    int bx = blockIdx.x, by = blockIdx.y, tid = threadIdx.x;
    if (tid < 64) {
        int n = perm[bx * 64 + tid];
        ns[tid] = n;
        float s = s_g[n];
        sa[tid] = __expf(s);
        sb[tid] = __expf(-s);
    }
    __syncthreads();
    int j = by * 256 + tid;
    float T[8] = {}, pre[8] = {};
    for (int c = 0; c < 64; ++c) {
        const float* cp = Cj + ((size_t)c * 2048 + j) * 8;
        float4 u0 = *(const float4*)cp, u1 = *(const float4*)(cp + 4);
        T[0] += u0.x; T[1] += u0.y; T[2] += u0.z; T[3] += u0.w;
        T[4] += u1.x; T[5] += u1.y; T[6] += u1.z; T[7] += u1.w;
        if (c < bx) {
            pre[0] += u0.x; pre[1] += u0.y; pre[2] += u0.z; pre[3] += u0.w;
            pre[4] += u1.x; pre[5] += u1.y; pre[6] += u1.z; pre[7] += u1.w;
        }
    }
    float TB[8] = {}, preb[8] = {};
    for (int c = 0; c < 64; ++c) {
        float4 v0 = *(const float4*)&Cb[c * 8], v1 = *(const float4*)&Cb[c * 8 + 4];
        TB[0] += v0.x; TB[1] += v0.y; TB[2] += v0.z; TB[3] += v0.w;
        TB[4] += v1.x; TB[5] += v1.y; TB[6] += v1.z; TB[7] += v1.w;
        if (c < bx) {
            preb[0] += v0.x; preb[1] += v0.y; preb[2] += v0.z; preb[3] += v0.w;
            preb[4] += v1.x; preb[5] += v1.y; preb[6] += v1.z; preb[7] += v1.w;
        }
    }
    for (int ii = 0; ii < 64; ++ii) {
        int n = ns[ii];
        float a = sa[ii], b = sb[ii];
        float g0 = 0.36787944117144233f;       // e^{-1}
        float g1 = g0 * a;
        float g2 = g1 * a * 0.5f;
        float g3 = g2 * a * (1.f / 3.f);
        float g4 = g3 * a * 0.25f;
        float g5 = g4 * a * 0.2f;
        float g6 = g5 * a * (1.f / 6.f);
        float g7 = g6 * a * (1.f / 7.f);
        float Z = a * preb[1]
                + g0 * (TB[0] - preb[0]) + g1 * (TB[1] - preb[1])
                + g2 * (TB[2] - preb[2]) + g3 * (TB[3] - preb[3])
                + g4 * (TB[4] - preb[4]) + g5 * (TB[5] - preb[5])
                + g6 * (TB[6] - preb[6]) + g7 * (TB[7] - preb[7]);
        float izv = 1.f / Z;
        float qv = qp[(size_t)n * 2048 + j];
        float ss2 = g0 * (T[0] - pre[0]) + g1 * (T[1] - pre[1])
                  + g2 * (T[2] - pre[2]) + g3 * (T[3] - pre[3])
                  + g4 * (T[4] - pre[4]) + g5 * (T[5] - pre[5])
                  + g6 * (T[6] - pre[6]) + g7 * (T[7] - pre[7]);
        float outv = (a * pre[1] + ss2) * izv + qv;
        qdifb[(size_t)n * 2048 + j] = f2b(outv);
        float bk = 1.f;
#pragma unroll
        for (int k2 = 0; k2 < 8; ++k2) { pre[k2] += bk * qv; preb[k2] += bk; bk *= b; }
    }
}

// ---------------- MFMA projection: Y[r,c] = sum_k X[r,k] W[c,k] + b[c] ----------------
__global__ __launch_bounds__(256) void k_projm(const float* __restrict__ X,
                                               const float* __restrict__ W,
                                               const float* __restrict__ bias,
                                               float* __restrict__ Y) {
    int tid = threadIdx.x, lane = tid & 63, wid = tid >> 6;
    int r0 = blockIdx.x * 256 + wid * 64;
    int l15 = lane & 15, kb = lane >> 4;
    f32x4 acc[4][4] = {};
#pragma unroll
    for (int ks = 0; ks < 2; ++ks) {
        short8 af[4], bf[4];
#pragma unroll
        for (int f = 0; f < 4; ++f) {
            const float* ap = X + (size_t)(r0 + f * 16 + l15) * 64 + ks * 32 + kb * 8;
            float4 x0 = *(const float4*)ap;
            float4 x1 = *(const float4*)(ap + 4);
            af[f] = pack8(x0, x1);
            const float* bp = W + (size_t)(f * 16 + l15) * 64 + ks * 32 + kb * 8;
            float4 w0 = *(const float4*)bp;
            float4 w1 = *(const float4*)(bp + 4);
            bf[f] = pack8(w0, w1);
        }
#pragma unroll
        for (int i = 0; i < 4; ++i)
#pragma unroll
            for (int j = 0; j < 4; ++j)
                acc[i][j] = MFMA16(af[i], bf[j], acc[i][j]);
    }
    float bcol[4];
#pragma unroll
    for (int j = 0; j < 4; ++j) bcol[j] = bias[j * 16 + l15];
#pragma unroll
    for (int i = 0; i < 4; ++i)
#pragma unroll
        for (int j = 0; j < 4; ++j)
#pragma unroll
            for (int r = 0; r < 4; ++r)
                Y[(size_t)(r0 + i * 16 + kb * 4 + r) * 64 + j * 16 + l15] = acc[i][j][r] + bcol[j];
}

// ---------------- transpose We: WeT[e][o][d] = We[e][d][o] ----------------
__global__ __launch_bounds__(256) void k_wet(const float* __restrict__ We,
                                             float* __restrict__ WeT) {
    __shared__ float t[64][65];
    int e = blockIdx.x, tid = threadIdx.x;
#pragma unroll
    for (int u = 0; u < 4; ++u) {
        int idx = tid + u * 256; int r = idx >> 4, c4 = (idx & 15) * 4;
        float4 v = *(const float4*)&We[(size_t)e * 4096 + r * 64 + c4];
        t[r][c4] = v.x; t[r][c4 + 1] = v.y; t[r][c4 + 2] = v.z; t[r][c4 + 3] = v.w;
    }
    __syncthreads();
#pragma unroll
    for (int u = 0; u < 4; ++u) {
        int idx = tid + u * 256; int r = idx >> 4, c4 = (idx & 15) * 4;
        float4 o;
        o.x = t[c4][r]; o.y = t[c4 + 1][r]; o.z = t[c4 + 2][r]; o.w = t[c4 + 3][r];
        *(float4*)&WeT[(size_t)e * 4096 + r * 64 + c4] = o;
    }
}

// ---------------- WnT[n][o*64+d] bf16 = sum_e emb[n,e] WeT[e][o*64+d] (4 nodes/block) ----
__global__ __launch_bounds__(256) void k_wnode(const float* __restrict__ emb,
                                               const float* __restrict__ WeT,
                                               ushort* __restrict__ WnT) {
    __shared__ float es[4 * DE];
    int tid = threadIdx.x;
    int n0 = blockIdx.x * 4;
    if (tid < 4 * DE) es[tid] = emb[n0 * DE + tid];
    __syncthreads();
    float a0[16] = {}, a1[16] = {}, a2[16] = {}, a3[16] = {};
    for (int e = 0; e < DE; ++e) {
        float w0 = es[e], w1 = es[DE + e], w2 = es[2 * DE + e], w3 = es[3 * DE + e];
        const float* row = WeT + (size_t)e * 4096;
#pragma unroll
        for (int i = 0; i < 16; ++i) {
            float t = row[i * 256 + tid];
            a0[i] += w0 * t; a1[i] += w1 * t; a2[i] += w2 * t; a3[i] += w3 * t;
        }
    }
#pragma unroll
    for (int i = 0; i < 16; ++i) {
        WnT[(size_t)n0 * 4096 + i * 256 + tid]       = f2b(a0[i]);
        WnT[(size_t)(n0 + 1) * 4096 + i * 256 + tid] = f2b(a1[i]);
        WnT[(size_t)(n0 + 2) * 4096 + i * 256 + tid] = f2b(a2[i]);
        WnT[(size_t)(n0 + 3) * 4096 + i * 256 + tid] = f2b(a3[i]);
    }
}

// ---------------- bnode[n,o] = sum_e emb[n,e] * be[e,o] ----------------
__global__ __launch_bounds__(256) void k_bnode(const float* __restrict__ emb,
                                               const float* __restrict__ be,
                                               float* __restrict__ bn) {
    int gid = blockIdx.x * 256 + threadIdx.x;
    int n = gid >> 6, o = gid & 63;
    float acc = 0.f;
#pragma unroll
    for (int e = 0; e < DE; ++e) acc += emb[n * DE + e] * be[e * 64 + o];
    bn[gid] = acc;
}

// ---------------- per-node MFMA: q2[n] = qdif[n](32x64) @ WnT[n]^T + bn[n] ----------------
__global__ __launch_bounds__(256) void k_nodemm(const ushort* __restrict__ qd,
                                                const ushort* __restrict__ WnT,
                                                const float* __restrict__ bn,
                                                float* __restrict__ q2) {
    int n = blockIdx.x;
    int tid = threadIdx.x, lane = tid & 63, wid = tid >> 6;
    int l15 = lane & 15, kb = lane >> 4;
    int fm = wid & 1;
    int fn0 = (wid >> 1) * 2;
    f32x4 acc[2] = {};
    const ushort* A = qd + (size_t)n * 2048;
    const ushort* B = WnT + (size_t)n * 4096;
#pragma unroll
    for (int ks = 0; ks < 2; ++ks) {
        short8 af = *(const short8*)(A + (fm * 16 + l15) * 64 + ks * 32 + kb * 8);
#pragma unroll
        for (int j = 0; j < 2; ++j) {
            short8 bf = *(const short8*)(B + (size_t)((fn0 + j) * 16 + l15) * 64 + ks * 32 + kb * 8);
            acc[j] = MFMA16(af, bf, acc[j]);
        }
    }
#pragma unroll
    for (int j = 0; j < 2; ++j) {
        int col = (fn0 + j) * 16 + l15;
        float bb = bn[n * 64 + col];
#pragma unroll
        for (int r = 0; r < 4; ++r) {
            int row = fm * 16 + kb * 4 + r;
            q2[(size_t)n * 2048 + row * 64 + col] = acc[j][r] + bb;
        }
    }
}

// ---------------- per-batch 8-head attention + Wo epilogue ----------------
__global__ __launch_bounds__(256) void k_attn(const float* __restrict__ q2,
                                              const float* __restrict__ kp,
                                              const float* __restrict__ vp,
                                              const float* __restrict__ Wo,
                                              const float* __restrict__ bo,
                                              float* __restrict__ out) {
    __shared__ float qs[32 * 68], ks[32 * 68], vs[32 * 68], att[32 * 68];
    __shared__ float wos[64 * 68];
    __shared__ float bos[64];
    int tid = threadIdx.x;
    int b = blockIdx.x;
    {
        int r = tid >> 3, c8 = (tid & 7) * 8;
        const float* s0 = q2 + (size_t)b * TD + r * 64 + c8;
        const float* s1 = kp + (size_t)b * TD + r * 64 + c8;
        const float* s2 = vp + (size_t)b * TD + r * 64 + c8;
        *(float4*)&qs[r * 68 + c8]     = *(const float4*)s0;
        *(float4*)&qs[r * 68 + c8 + 4] = *(const float4*)(s0 + 4);
        *(float4*)&ks[r * 68 + c8]     = *(const float4*)s1;
        *(float4*)&ks[r * 68 + c8 + 4] = *(const float4*)(s1 + 4);
        *(float4*)&vs[r * 68 + c8]     = *(const float4*)s2;
        *(float4*)&vs[r * 68 + c8 + 4] = *(const float4*)(s2 + 4);
    }
#pragma unroll
    for (int u = 0; u < 4; ++u) {
        int idx = tid + u * 256; int r = idx >> 4, c4 = (idx & 15) * 4;
        *(float4*)&wos[r * 68 + c4] = *(const float4*)&Wo[idx * 4];
    }
    if (tid < 64) bos[tid] = bo[tid];
    __syncthreads();
    int h = tid >> 5, tq = tid & 31;
    float4 q0 = *(const float4*)&qs[tq * 68 + h * 8];
    float4 q1 = *(const float4*)&qs[tq * 68 + h * 8 + 4];
    float sc[32]; float mx = -1e30f;
#pragma unroll
    for (int s_ = 0; s_ < 32; ++s_) {
        float4 k0 = *(const float4*)&ks[s_ * 68 + h * 8];
        float4 k1 = *(const float4*)&ks[s_ * 68 + h * 8 + 4];
        float dot = q0.x * k0.x + q0.y * k0.y + q0.z * k0.z + q0.w * k0.w
                  + q1.x * k1.x + q1.y * k1.y + q1.z * k1.z + q1.w * k1.w;
        dot *= 0.35355339059327373f;
        sc[s_] = dot; mx = fmaxf(mx, dot);
    }
    float sum = 0.f;
#pragma unroll
    for (int s_ = 0; s_ < 32; ++s_) { float e = __expf(sc[s_] - mx); sc[s_] = e; sum += e; }
    float inv = 1.f / sum;
    float oa[8] = {};
#pragma unroll
    for (int s_ = 0; s_ < 32; ++s_) {
        float w = sc[s_];
        float4 v0 = *(const float4*)&vs[s_ * 68 + h * 8];
        float4 v1 = *(const float4*)&vs[s_ * 68 + h * 8 + 4];
        oa[0] += w * v0.x; oa[1] += w * v0.y; oa[2] += w * v0.z; oa[3] += w * v0.w;
        oa[4] += w * v1.x; oa[5] += w * v1.y; oa[6] += w * v1.z; oa[7] += w * v1.w;
    }
    float4 w0 = make_float4(oa[0] * inv, oa[1] * inv, oa[2] * inv, oa[3] * inv);
    float4 w1 = make_float4(oa[4] * inv, oa[5] * inv, oa[6] * inv, oa[7] * inv);
    *(float4*)&att[tq * 68 + h * 8]     = w0;
    *(float4*)&att[tq * 68 + h * 8 + 4] = w1;
    __syncthreads();
    int rp = tid & 15, g = tid >> 4;
    float a0[4] = {}, a1[4] = {};
#pragma unroll
    for (int d4 = 0; d4 < 16; ++d4) {
        float4 x0 = *(const float4*)&att[rp * 68 + d4 * 4];
        float4 x1 = *(const float4*)&att[(rp + 16) * 68 + d4 * 4];
#pragma unroll
        for (int i = 0; i < 4; ++i) {
            float4 w = *(const float4*)&wos[(g * 4 + i) * 68 + d4 * 4];
            a0[i] += x0.x * w.x + x0.y * w.y + x0.z * w.z + x0.w * w.w;
            a1[i] += x1.x * w.x + x1.y * w.y + x1.z * w.z + x1.w * w.w;
        }
    }
    float4 r0 = make_float4(a0[0] + bos[g * 4], a0[1] + bos[g * 4 + 1],
                            a0[2] + bos[g * 4 + 2], a0[3] + bos[g * 4 + 3]);
    float4 r1 = make_float4(a1[0] + bos[g * 4], a1[1] + bos[g * 4 + 1],
                            a1[2] + bos[g * 4 + 2], a1[3] + bos[g * 4 + 3]);
    *(float4*)&out[(size_t)b * TD + rp * 64 + g * 4]        = r0;
    *(float4*)&out[(size_t)b * TD + (rp + 16) * 64 + g * 4] = r1;
}

extern "C" void kernel_launch(void* const* d_in, const int* in_sizes, int n_in,
                              void* d_out, int out_size, void* d_ws, size_t ws_size,
                              hipStream_t stream) {
    const float* q   = (const float*)d_in[0];
    const float* k   = (const float*)d_in[1];
    const float* v   = (const float*)d_in[2];
    const float* emb = (const float*)d_in[3];
    const float* We  = (const float*)d_in[4];
    const float* be  = (const float*)d_in[5];
    const float* Wq  = (const float*)d_in[6];
    const float* bq  = (const float*)d_in[7];
    const float* Wk  = (const float*)d_in[8];
    const float* bk  = (const float*)d_in[9];
    const float* Wv  = (const float*)d_in[10];
    const float* bv  = (const float*)d_in[11];
    const float* Wo  = (const float*)d_in[12];
    const float* bo  = (const float*)d_in[13];

    float* ws = (float*)d_ws;
    float*  qp    = ws;                                   // [0, 8388608)  (q2 later)
    float*  kp    = ws + 8388608;
    float*  vp    = ws + 16777216;
    ushort* WnT   = (ushort*)(ws + 25165824);             // 32 MB
    ushort* qdifb = (ushort*)(ws + 33554432);             // 16 MB
    float*  bn    = ws + 37748736;                        // 1 MB
    float*  s_g   = ws + 38010880;                        // 16 KB
    float*  WeT   = ws + 38014976;                        // 512 KB
    int*    perm  = (int*)(ws + 38146048);                // 16 KB
    float*  Cb    = ws + 38150144;                        // 2 KB
    float*  Cj    = ws + 38150656;                        // 4 MB (end = 156.8 MB)
    float*  q2    = qp;                                   // qp dead after k_comb
    float*  outp  = (float*)d_out;

    k_s    <<<16, 256, 0, stream>>>(emb, s_g);
    k_rank <<<512, 256, 0, stream>>>(s_g, perm);
    k_projm<<<512, 256, 0, stream>>>(q, Wq, bq, qp);
    k_csum <<<dim3(64, 8), 256, 0, stream>>>(qp, s_g, perm, Cj, Cb);
    k_comb <<<dim3(64, 8), 256, 0, stream>>>(qp, s_g, perm, Cj, Cb, qdifb);
    k_projm<<<512, 256, 0, stream>>>(k, Wk, bk, kp);
    k_projm<<<512, 256, 0, stream>>>(v, Wv, bv, vp);
    k_wet  <<<32, 256, 0, stream>>>(We, WeT);
    k_wnode<<<1024, 256, 0, stream>>>(emb, WeT, WnT);
    k_bnode<<<1024, 256, 0, stream>>>(emb, be, bn);
    k_nodemm<<<4096, 256, 0, stream>>>(qdifb, WnT, bn, q2);
    k_attn <<<4096, 256, 0, stream>>>(q2, kp, vp, Wo, bo, outp);
}

// Round 4
// 178.733 us; speedup vs baseline: 11.2975x; 1.2484x over previous
//
#include <hip/hip_runtime.h>
#include <hip/hip_bf16.h>

constexpr int NN  = 4096;       // n_node + 1 == batch
constexpr int DE  = 32;         // d_emb
constexpr int TD  = 2048;       // T*D

typedef __attribute__((ext_vector_type(8))) short short8;
typedef __attribute__((ext_vector_type(4))) float f32x4;

#define MFMA16(a, b, c) __builtin_amdgcn_mfma_f32_16x16x32_bf16(a, b, c, 0, 0, 0)

__device__ inline ushort f2b(float x) {
    union { float f; unsigned u; } c; c.f = x;
    unsigned r = (c.u + 0x7FFF + ((c.u >> 16) & 1)) >> 16;
    return (ushort)r;
}

__device__ inline short8 pack8(float4 a, float4 b) {
    short8 v;
    v[0] = (short)f2b(a.x); v[1] = (short)f2b(a.y); v[2] = (short)f2b(a.z); v[3] = (short)f2b(a.w);
    v[4] = (short)f2b(b.x); v[5] = (short)f2b(b.y); v[6] = (short)f2b(b.z); v[7] = (short)f2b(b.w);
    return v;
}

// ---------------- generic f32 -> bf16 ----------------
__global__ __launch_bounds__(256) void k_cvt(const float* __restrict__ src,
                                             ushort* __restrict__ dst, int n) {
    int gid = blockIdx.x * 256 + threadIdx.x;
    if (gid < n) dst[gid] = f2b(src[gid]);
}

// ---------------- s[n] = sum_e emb[n,e] ----------------
__global__ __launch_bounds__(256) void k_s(const float* __restrict__ emb,
                                           float* __restrict__ s_g) {
    int n = blockIdx.x * 256 + threadIdx.x;
    const float4* e4 = (const float4*)(emb + n * DE);
    float s = 0.f;
#pragma unroll
    for (int i = 0; i < DE / 4; ++i) { float4 v = e4[i]; s += v.x + v.y + v.z + v.w; }
    s_g[n] = s;
}

// ---------------- rank[n] = #{m: (s_m,m) < (s_n,n)}; perm[rank]=n ----------------
__global__ __launch_bounds__(256) void k_rank(const float* __restrict__ s_g,
                                              int* __restrict__ perm) {
    __shared__ float ss[NN];
    int tid = threadIdx.x;
    for (int i = tid; i < NN; i += 256) ss[i] = s_g[i];
    __syncthreads();
    int g = tid >> 5, l = tid & 31;
    int n = blockIdx.x * 8 + g;
    float sn = ss[n];
    int cnt = 0;
    for (int j2 = 0; j2 < 128; ++j2) {
        int m = j2 * 32 + l;
        float sm = ss[m];
        cnt += (sm < sn) || (sm == sn && m < n);
    }
    for (int off = 16; off; off >>= 1) cnt += __shfl_down(cnt, off, 32);
    if (l == 0) perm[cnt] = n;
}

// ---------------- chunk sums: Cj[c][j][k] = sum_{i in chunk c} b^k * q[perm[i]][j] ------
__global__ __launch_bounds__(256) void k_csum(const float* __restrict__ qp,
                                              const float* __restrict__ s_g,
                                              const int* __restrict__ perm,
                                              float* __restrict__ Cj,
                                              float* __restrict__ Cb) {
    __shared__ int ns[64];
    __shared__ float bs[64];
    int bx = blockIdx.x, by = blockIdx.y, tid = threadIdx.x;
    if (tid < 64) {
        int n = perm[bx * 64 + tid];
        ns[tid] = n;
        bs[tid] = __expf(-s_g[n]);
    }
    __syncthreads();
    int j = by * 256 + tid;
    float run[8] = {};
    for (int ii = 0; ii < 64; ++ii) {
        float qv = qp[(size_t)ns[ii] * 2048 + j];
        float b = bs[ii], t = qv;
#pragma unroll
        for (int k2 = 0; k2 < 8; ++k2) { run[k2] += t; t *= b; }
    }
    float* cp = Cj + ((size_t)bx * 2048 + j) * 8;
    *(float4*)cp       = make_float4(run[0], run[1], run[2], run[3]);
    *(float4*)(cp + 4) = make_float4(run[4], run[5], run[6], run[7]);
    if (by == 0 && tid < 64) {
        float b = bs[tid], bk = 1.f;
#pragma unroll
        for (int k2 = 0; k2 < 8; ++k2) {
            float v = bk;
            for (int off = 32; off; off >>= 1) v += __shfl_down(v, off, 64);
            if (tid == 0) Cb[bx * 8 + k2] = v;
            bk *= b;
        }
    }
}

// ---------------- combine: qdif[n,j] = invZ*(a*pre1 + sum_k g_k (T_k - pre_k)) + q -------
__global__ __launch_bounds__(256) void k_comb(const float* __restrict__ qp,
                                              const float* __restrict__ s_g,
                                              const int* __restrict__ perm,
                                              const float* __restrict__ Cj,
                                              const float* __restrict__ Cb,
                                              ushort* __restrict__ qdifb) {
    __shared__ int ns[64];
    __shared__ float sa[64], sb[64];
    int bx = blockIdx.x, by = blockIdx.y, tid = threadIdx.x;
    if (tid < 64) {
        int n = perm[bx * 64 + tid];
        ns[tid] = n;
        float s = s_g[n];
        sa[tid] = __expf(s);
        sb[tid] = __expf(-s);
    }
    __syncthreads();
    int j = by * 256 + tid;
    float T[8] = {}, pre[8] = {};
    for (int c = 0; c < 64; ++c) {
        const float* cp = Cj + ((size_t)c * 2048 + j) * 8;
        float4 u0 = *(const float4*)cp, u1 = *(const float4*)(cp + 4);
        T[0] += u0.x; T[1] += u0.y; T[2] += u0.z; T[3] += u0.w;
        T[4] += u1.x; T[5] += u1.y; T[6] += u1.z; T[7] += u1.w;
        if (c < bx) {
            pre[0] += u0.x; pre[1] += u0.y; pre[2] += u0.z; pre[3] += u0.w;
            pre[4] += u1.x; pre[5] += u1.y; pre[6] += u1.z; pre[7] += u1.w;
        }
    }
    float TB[8] = {}, preb[8] = {};
    for (int c = 0; c < 64; ++c) {
        float4 v0 = *(const float4*)&Cb[c * 8], v1 = *(const float4*)&Cb[c * 8 + 4];
        TB[0] += v0.x; TB[1] += v0.y; TB[2] += v0.z; TB[3] += v0.w;
        TB[4] += v1.x; TB[5] += v1.y; TB[6] += v1.z; TB[7] += v1.w;
        if (c < bx) {
            preb[0] += v0.x; preb[1] += v0.y; preb[2] += v0.z; preb[3] += v0.w;
            preb[4] += v1.x; preb[5] += v1.y; preb[6] += v1.z; preb[7] += v1.w;
        }
    }
    for (int ii = 0; ii < 64; ++ii) {
        int n = ns[ii];
        float a = sa[ii], b = sb[ii];
        float g0 = 0.36787944117144233f;       // e^{-1}
        float g1 = g0 * a;
        float g2 = g1 * a * 0.5f;
        float g3 = g2 * a * (1.f / 3.f);
        float g4 = g3 * a * 0.25f;
        float g5 = g4 * a * 0.2f;
        float g6 = g5 * a * (1.f / 6.f);
        float g7 = g6 * a * (1.f / 7.f);
        float Z = a * preb[1]
                + g0 * (TB[0] - preb[0]) + g1 * (TB[1] - preb[1])
                + g2 * (TB[2] - preb[2]) + g3 * (TB[3] - preb[3])
                + g4 * (TB[4] - preb[4]) + g5 * (TB[5] - preb[5])
                + g6 * (TB[6] - preb[6]) + g7 * (TB[7] - preb[7]);
        float izv = 1.f / Z;
        float qv = qp[(size_t)n * 2048 + j];
        float ss2 = g0 * (T[0] - pre[0]) + g1 * (T[1] - pre[1])
                  + g2 * (T[2] - pre[2]) + g3 * (T[3] - pre[3])
                  + g4 * (T[4] - pre[4]) + g5 * (T[5] - pre[5])
                  + g6 * (T[6] - pre[6]) + g7 * (T[7] - pre[7]);
        float outv = (a * pre[1] + ss2) * izv + qv;
        qdifb[(size_t)n * 2048 + j] = f2b(outv);
        float bk = 1.f;
#pragma unroll
        for (int k2 = 0; k2 < 8; ++k2) { pre[k2] += bk * qv; preb[k2] += bk; bk *= b; }
    }
}

// ---------------- MFMA projection (q only): Y[r,c] = sum_k X[r,k] W[c,k] + b[c] ---------
__global__ __launch_bounds__(256) void k_projm(const float* __restrict__ X,
                                               const float* __restrict__ W,
                                               const float* __restrict__ bias,
                                               float* __restrict__ Y) {
    int tid = threadIdx.x, lane = tid & 63, wid = tid >> 6;
    int r0 = blockIdx.x * 256 + wid * 64;
    int l15 = lane & 15, kb = lane >> 4;
    f32x4 acc[4][4] = {};
#pragma unroll
    for (int kk = 0; kk < 2; ++kk) {
        short8 af[4], bf[4];
#pragma unroll
        for (int f = 0; f < 4; ++f) {
            const float* ap = X + (size_t)(r0 + f * 16 + l15) * 64 + kk * 32 + kb * 8;
            af[f] = pack8(*(const float4*)ap, *(const float4*)(ap + 4));
            const float* bp = W + (size_t)(f * 16 + l15) * 64 + kk * 32 + kb * 8;
            bf[f] = pack8(*(const float4*)bp, *(const float4*)(bp + 4));
        }
#pragma unroll
        for (int i = 0; i < 4; ++i)
#pragma unroll
            for (int j = 0; j < 4; ++j)
                acc[i][j] = MFMA16(af[i], bf[j], acc[i][j]);
    }
    float bcol[4];
#pragma unroll
    for (int j = 0; j < 4; ++j) bcol[j] = bias[j * 16 + l15];
#pragma unroll
    for (int i = 0; i < 4; ++i)
#pragma unroll
        for (int j = 0; j < 4; ++j)
#pragma unroll
            for (int r = 0; r < 4; ++r)
                Y[(size_t)(r0 + i * 16 + kb * 4 + r) * 64 + j * 16 + l15] = acc[i][j][r] + bcol[j];
}

// ---------------- WeTT[od][e] = We[e][d*64+o] bf16 (od = o*64+d) ----------------
__global__ __launch_bounds__(256) void k_wett(const float* __restrict__ We,
                                              ushort* __restrict__ WeTT) {
    int gid = blockIdx.x * 256 + threadIdx.x;   // 131072
    int od = gid >> 5, e = gid & 31;
    int o = od >> 6, d = od & 63;
    WeTT[gid] = f2b(We[(size_t)e * 4096 + d * 64 + o]);
}

// ---------------- Wn GEMM: WnT[n][od] = sum_e embbf[n][e] * WeTT[od][e] ----------------
__global__ __launch_bounds__(256) void k_wnodem(const ushort* __restrict__ embbf,
                                                const ushort* __restrict__ WeTT,
                                                ushort* __restrict__ WnT) {
    int tid = threadIdx.x, lane = tid & 63, wid = tid >> 6;
    int n0  = blockIdx.x * 128 + (wid >> 1) * 64;
    int od0 = blockIdx.y * 128 + (wid & 1) * 64;
    int l15 = lane & 15, kb = lane >> 4;
    short8 af[4], bf[4];
#pragma unroll
    for (int f = 0; f < 4; ++f) {
        af[f] = *(const short8*)(embbf + (size_t)(n0 + f * 16 + l15) * 32 + kb * 8);
        bf[f] = *(const short8*)(WeTT + (size_t)(od0 + f * 16 + l15) * 32 + kb * 8);
    }
    f32x4 acc[4][4] = {};
#pragma unroll
    for (int i = 0; i < 4; ++i)
#pragma unroll
        for (int j = 0; j < 4; ++j)
            acc[i][j] = MFMA16(af[i], bf[j], acc[i][j]);
#pragma unroll
    for (int i = 0; i < 4; ++i)
#pragma unroll
        for (int j = 0; j < 4; ++j)
#pragma unroll
            for (int r = 0; r < 4; ++r)
                WnT[(size_t)(n0 + i * 16 + kb * 4 + r) * 4096 + od0 + j * 16 + l15] =
                    f2b(acc[i][j][r]);
}

// ---------------- bnode[n,o] = sum_e emb[n,e] * be[e,o] ----------------
__global__ __launch_bounds__(256) void k_bnode(const float* __restrict__ emb,
                                               const float* __restrict__ be,
                                               float* __restrict__ bn) {
    int gid = blockIdx.x * 256 + threadIdx.x;
    int n = gid >> 6, o = gid & 63;
    float acc = 0.f;
#pragma unroll
    for (int e = 0; e < DE; ++e) acc += emb[n * DE + e] * be[e * 64 + o];
    bn[gid] = acc;
}

// ---------------- fused per-batch: kp/vp/q2 MFMA -> VALU attention -> MFMA epilogue ------
__global__ __launch_bounds__(256) void k_fused(const float* __restrict__ kin,
                                               const float* __restrict__ vin,
                                               const ushort* __restrict__ qdifb,
                                               const ushort* __restrict__ WnT,
                                               const float* __restrict__ bn,
                                               const ushort* __restrict__ Wkbf,
                                               const float* __restrict__ bk,
                                               const ushort* __restrict__ Wvbf,
                                               const float* __restrict__ bv,
                                               const ushort* __restrict__ Wobf,
                                               const float* __restrict__ bo,
                                               float* __restrict__ out) {
    __shared__ float qs_s[32 * 68], ks_s[32 * 68], vs_s[32 * 68], att_s[32 * 68];
    int tid = threadIdx.x, lane = tid & 63, w = tid >> 6;
    int b = blockIdx.x;
    int l15 = lane & 15, kb = lane >> 4;
    int col = w * 16 + l15;

    // ---- phase 1: kp = k@Wk^T+bk, vp = v@Wv^T+bv, q2 = qdif@Wn^T+bn (wave w: cols col)
    f32x4 ck[2] = {}, cv[2] = {}, cq[2] = {};
#pragma unroll
    for (int kk = 0; kk < 2; ++kk) {
        short8 bkf = *(const short8*)(Wkbf + (size_t)col * 64 + kk * 32 + kb * 8);
        short8 bvf = *(const short8*)(Wvbf + (size_t)col * 64 + kk * 32 + kb * 8);
        short8 bqf = *(const short8*)(WnT + (size_t)b * 4096 + (size_t)col * 64 + kk * 32 + kb * 8);
#pragma unroll
        for (int ti = 0; ti < 2; ++ti) {
            const float* ap = kin + (size_t)b * TD + (ti * 16 + l15) * 64 + kk * 32 + kb * 8;
            short8 ak = pack8(*(const float4*)ap, *(const float4*)(ap + 4));
            const float* vp_ = vin + (size_t)b * TD + (ti * 16 + l15) * 64 + kk * 32 + kb * 8;
            short8 av = pack8(*(const float4*)vp_, *(const float4*)(vp_ + 4));
            short8 aq = *(const short8*)(qdifb + (size_t)b * TD + (ti * 16 + l15) * 64 + kk * 32 + kb * 8);
            ck[ti] = MFMA16(ak, bkf, ck[ti]);
            cv[ti] = MFMA16(av, bvf, cv[ti]);
            cq[ti] = MFMA16(aq, bqf, cq[ti]);
        }
    }
    float bkc = bk[col], bvc = bv[col], bnc = bn[b * 64 + col];
#pragma unroll
    for (int ti = 0; ti < 2; ++ti)
#pragma unroll
        for (int r = 0; r < 4; ++r) {
            int row = ti * 16 + kb * 4 + r;
            ks_s[row * 68 + col] = ck[ti][r] + bkc;
            vs_s[row * 68 + col] = cv[ti][r] + bvc;
            qs_s[row * 68 + col] = cq[ti][r] + bnc;
        }
    __syncthreads();

    // ---- phase 2: VALU 8-head attention (h = tid>>5, tq = tid&31)
    int h = tid >> 5, tq = tid & 31;
    float4 q0 = *(const float4*)&qs_s[tq * 68 + h * 8];
    float4 q1 = *(const float4*)&qs_s[tq * 68 + h * 8 + 4];
    float sc[32]; float mx = -1e30f;
#pragma unroll
    for (int s_ = 0; s_ < 32; ++s_) {
        float4 k0 = *(const float4*)&ks_s[s_ * 68 + h * 8];
        float4 k1 = *(const float4*)&ks_s[s_ * 68 + h * 8 + 4];
        float dot = q0.x * k0.x + q0.y * k0.y + q0.z * k0.z + q0.w * k0.w
                  + q1.x * k1.x + q1.y * k1.y + q1.z * k1.z + q1.w * k1.w;
        dot *= 0.35355339059327373f;
        sc[s_] = dot; mx = fmaxf(mx, dot);
    }
    float sum = 0.f;
#pragma unroll
    for (int s_ = 0; s_ < 32; ++s_) { float e = __expf(sc[s_] - mx); sc[s_] = e; sum += e; }
    float inv = 1.f / sum;
    float oa[8] = {};
#pragma unroll
    for (int s_ = 0; s_ < 32; ++s_) {
        float wgt = sc[s_];
        float4 v0 = *(const float4*)&vs_s[s_ * 68 + h * 8];
        float4 v1 = *(const float4*)&vs_s[s_ * 68 + h * 8 + 4];
        oa[0] += wgt * v0.x; oa[1] += wgt * v0.y; oa[2] += wgt * v0.z; oa[3] += wgt * v0.w;
        oa[4] += wgt * v1.x; oa[5] += wgt * v1.y; oa[6] += wgt * v1.z; oa[7] += wgt * v1.w;
    }
    *(float4*)&att_s[tq * 68 + h * 8]     = make_float4(oa[0] * inv, oa[1] * inv, oa[2] * inv, oa[3] * inv);
    *(float4*)&att_s[tq * 68 + h * 8 + 4] = make_float4(oa[4] * inv, oa[5] * inv, oa[6] * inv, oa[7] * inv);
    __syncthreads();

    // ---- phase 3: MFMA epilogue out = att @ Wo^T + bo (wave w: cols col)
    f32x4 co[2] = {};
#pragma unroll
    for (int kk = 0; kk < 2; ++kk) {
        short8 bof = *(const short8*)(Wobf + (size_t)col * 64 + kk * 32 + kb * 8);
#pragma unroll
        for (int ti = 0; ti < 2; ++ti) {
            const float* ap = &att_s[(ti * 16 + l15) * 68 + kk * 32 + kb * 8];
            short8 aof = pack8(*(const float4*)ap, *(const float4*)(ap + 4));
            co[ti] = MFMA16(aof, bof, co[ti]);
        }
    }
    float boc = bo[col];
#pragma unroll
    for (int ti = 0; ti < 2; ++ti)
#pragma unroll
        for (int r = 0; r < 4; ++r)
            out[(size_t)b * TD + (ti * 16 + kb * 4 + r) * 64 + col] = co[ti][r] + boc;
}

extern "C" void kernel_launch(void* const* d_in, const int* in_sizes, int n_in,
                              void* d_out, int out_size, void* d_ws, size_t ws_size,
                              hipStream_t stream) {
    const float* q   = (const float*)d_in[0];
    const float* k   = (const float*)d_in[1];
    const float* v   = (const float*)d_in[2];
    const float* emb = (const float*)d_in[3];
    const float* We  = (const float*)d_in[4];
    const float* be  = (const float*)d_in[5];
    const float* Wq  = (const float*)d_in[6];
    const float* bq  = (const float*)d_in[7];
    const float* Wk  = (const float*)d_in[8];
    const float* bk  = (const float*)d_in[9];
    const float* Wv  = (const float*)d_in[10];
    const float* bv  = (const float*)d_in[11];
    const float* Wo  = (const float*)d_in[12];
    const float* bo  = (const float*)d_in[13];

    float* ws = (float*)d_ws;
    float*  qp    = ws;                                   // 32 MB
    ushort* WnT   = (ushort*)(ws + 8388608);              // 32 MB
    ushort* qdifb = (ushort*)(ws + 16777216);             // 16 MB
    float*  Cj    = ws + 20971520;                        // 4 MB
    float*  bn    = ws + 22020096;                        // 1 MB
    float*  s_g   = ws + 22282240;                        // 16 KB
    int*    perm  = (int*)(ws + 22286336);                // 16 KB
    float*  Cb    = ws + 22290432;                        // 2 KB
    ushort* embbf = (ushort*)(ws + 22290944);             // 256 KB
    ushort* WeTT  = (ushort*)(ws + 22356480);             // 256 KB
    ushort* Wkbf  = (ushort*)(ws + 22422016);             // 8 KB
    ushort* Wvbf  = (ushort*)(ws + 22424064);             // 8 KB
    ushort* Wobf  = (ushort*)(ws + 22426112);             // 8 KB (end ~85.6 MB)
    float*  outp  = (float*)d_out;

    k_s    <<<16, 256, 0, stream>>>(emb, s_g);
    k_rank <<<512, 256, 0, stream>>>(s_g, perm);
    k_cvt  <<<512, 256, 0, stream>>>(emb, embbf, 131072);
    k_wett <<<512, 256, 0, stream>>>(We, WeTT);
    k_cvt  <<<16, 256, 0, stream>>>(Wk, Wkbf, 4096);
    k_cvt  <<<16, 256, 0, stream>>>(Wv, Wvbf, 4096);
    k_cvt  <<<16, 256, 0, stream>>>(Wo, Wobf, 4096);
    k_projm<<<512, 256, 0, stream>>>(q, Wq, bq, qp);
    k_csum <<<dim3(64, 8), 256, 0, stream>>>(qp, s_g, perm, Cj, Cb);
    k_comb <<<dim3(64, 8), 256, 0, stream>>>(qp, s_g, perm, Cj, Cb, qdifb);
    k_wnodem<<<dim3(32, 32), 256, 0, stream>>>(embbf, WeTT, WnT);
    k_bnode<<<1024, 256, 0, stream>>>(emb, be, bn);
    k_fused<<<4096, 256, 0, stream>>>(k, v, qdifb, WnT, bn,
                                      Wkbf, bk, Wvbf, bv, Wobf, bo, outp);
}

// Round 5
// 169.713 us; speedup vs baseline: 11.8979x; 1.0532x over previous
//
#include <hip/hip_runtime.h>
#include <hip/hip_bf16.h>

constexpr int NN  = 4096;       // n_node + 1 == batch
constexpr int DE  = 32;         // d_emb
constexpr int TD  = 2048;       // T*D

typedef __attribute__((ext_vector_type(8))) short short8;
typedef __attribute__((ext_vector_type(4))) float f32x4;

#define MFMA16(a, b, c) __builtin_amdgcn_mfma_f32_16x16x32_bf16(a, b, c, 0, 0, 0)

__device__ inline ushort f2b(float x) {
    union { float f; unsigned u; } c; c.f = x;
    unsigned r = (c.u + 0x7FFF + ((c.u >> 16) & 1)) >> 16;
    return (ushort)r;
}

__device__ inline short8 pack8(float4 a, float4 b) {
    short8 v;
    v[0] = (short)f2b(a.x); v[1] = (short)f2b(a.y); v[2] = (short)f2b(a.z); v[3] = (short)f2b(a.w);
    v[4] = (short)f2b(b.x); v[5] = (short)f2b(b.y); v[6] = (short)f2b(b.z); v[7] = (short)f2b(b.w);
    return v;
}

// ---------------- generic f32 -> bf16 ----------------
__global__ __launch_bounds__(256) void k_cvt(const float* __restrict__ src,
                                             ushort* __restrict__ dst, int n) {
    int gid = blockIdx.x * 256 + threadIdx.x;
    if (gid < n) dst[gid] = f2b(src[gid]);
}

// ---------------- s[n] = sum_e emb[n,e] ----------------
__global__ __launch_bounds__(256) void k_s(const float* __restrict__ emb,
                                           float* __restrict__ s_g) {
    int n = blockIdx.x * 256 + threadIdx.x;
    const float4* e4 = (const float4*)(emb + n * DE);
    float s = 0.f;
#pragma unroll
    for (int i = 0; i < DE / 4; ++i) { float4 v = e4[i]; s += v.x + v.y + v.z + v.w; }
    s_g[n] = s;
}

// ---------------- rank[n] = #{m: (s_m,m) < (s_n,n)}; perm[rank]=n ----------------
__global__ __launch_bounds__(256) void k_rank(const float* __restrict__ s_g,
                                              int* __restrict__ perm) {
    __shared__ float ss[NN];
    int tid = threadIdx.x;
    for (int i = tid; i < NN; i += 256) ss[i] = s_g[i];
    __syncthreads();
    int g = tid >> 5, l = tid & 31;
    int n = blockIdx.x * 8 + g;
    float sn = ss[n];
    int cnt = 0;
    for (int j2 = 0; j2 < 128; ++j2) {
        int m = j2 * 32 + l;
        float sm = ss[m];
        cnt += (sm < sn) || (sm == sn && m < n);
    }
    for (int off = 16; off; off >>= 1) cnt += __shfl_down(cnt, off, 32);
    if (l == 0) perm[cnt] = n;
}

// ---------------- chunk sums: Cj[c][j][k] = sum_{i in chunk c} b^k * q[perm[i]][j] ------
__global__ __launch_bounds__(256) void k_csum(const float* __restrict__ qp,
                                              const float* __restrict__ s_g,
                                              const int* __restrict__ perm,
                                              float* __restrict__ Cj,
                                              float* __restrict__ Cb) {
    __shared__ int ns[64];
    __shared__ float bs[64];
    int bx = blockIdx.x, by = blockIdx.y, tid = threadIdx.x;
    if (tid < 64) {
        int n = perm[bx * 64 + tid];
        ns[tid] = n;
        bs[tid] = __expf(-s_g[n]);
    }
    __syncthreads();
    int j = by * 256 + tid;
    float run[8] = {};
    for (int ii = 0; ii < 64; ++ii) {
        float qv = qp[(size_t)ns[ii] * 2048 + j];
        float b = bs[ii], t = qv;
#pragma unroll
        for (int k2 = 0; k2 < 8; ++k2) { run[k2] += t; t *= b; }
    }
    float* cp = Cj + ((size_t)bx * 2048 + j) * 8;
    *(float4*)cp       = make_float4(run[0], run[1], run[2], run[3]);
    *(float4*)(cp + 4) = make_float4(run[4], run[5], run[6], run[7]);
    if (by == 0 && tid < 64) {
        float b = bs[tid], bk = 1.f;
#pragma unroll
        for (int k2 = 0; k2 < 8; ++k2) {
            float v = bk;
            for (int off = 32; off; off >>= 1) v += __shfl_down(v, off, 64);
            if (tid == 0) Cb[bx * 8 + k2] = v;
            bk *= b;
        }
    }
}

// ---------------- prefix over chunks: PRE[c][j][k] = sum_{c'<c} Cj[c'][j][k] ----------
__global__ __launch_bounds__(256) void k_pre(const float* __restrict__ Cj,
                                             float* __restrict__ PRE) {
    int gid = blockIdx.x * 256 + threadIdx.x;      // 16384: j = gid>>3, k = gid&7
    float run = 0.f;
    for (int c = 0; c < 64; ++c) {
        PRE[(size_t)c * 16384 + gid] = run;
        run += Cj[(size_t)c * 16384 + gid];
    }
    PRE[(size_t)64 * 16384 + gid] = run;
}

// ---------------- combine: qdif[n,j] = invZ*(a*pre1 + sum_k g_k (T_k - pre_k)) + q -------
__global__ __launch_bounds__(256) void k_comb(const float* __restrict__ qp,
                                              const float* __restrict__ s_g,
                                              const int* __restrict__ perm,
                                              const float* __restrict__ PRE,
                                              const float* __restrict__ Cb,
                                              ushort* __restrict__ qdifb) {
    __shared__ int ns[64];
    __shared__ float sa[64], sb[64];
    int bx = blockIdx.x, by = blockIdx.y, tid = threadIdx.x;
    if (tid < 64) {
        int n = perm[bx * 64 + tid];
        ns[tid] = n;
        float s = s_g[n];
        sa[tid] = __expf(s);
        sb[tid] = __expf(-s);
    }
    __syncthreads();
    int j = by * 256 + tid;
    float T[8], pre[8];
    {
        const float* pp = PRE + (size_t)bx * 16384 + (size_t)j * 8;
        float4 u0 = *(const float4*)pp, u1 = *(const float4*)(pp + 4);
        pre[0] = u0.x; pre[1] = u0.y; pre[2] = u0.z; pre[3] = u0.w;
        pre[4] = u1.x; pre[5] = u1.y; pre[6] = u1.z; pre[7] = u1.w;
        const float* tp = PRE + (size_t)64 * 16384 + (size_t)j * 8;
        float4 t0 = *(const float4*)tp, t1 = *(const float4*)(tp + 4);
        T[0] = t0.x; T[1] = t0.y; T[2] = t0.z; T[3] = t0.w;
        T[4] = t1.x; T[5] = t1.y; T[6] = t1.z; T[7] = t1.w;
    }
    float TB[8] = {}, preb[8] = {};
    for (int c = 0; c < 64; ++c) {
        float4 v0 = *(const float4*)&Cb[c * 8], v1 = *(const float4*)&Cb[c * 8 + 4];
        TB[0] += v0.x; TB[1] += v0.y; TB[2] += v0.z; TB[3] += v0.w;
        TB[4] += v1.x; TB[5] += v1.y; TB[6] += v1.z; TB[7] += v1.w;
        if (c < bx) {
            preb[0] += v0.x; preb[1] += v0.y; preb[2] += v0.z; preb[3] += v0.w;
            preb[4] += v1.x; preb[5] += v1.y; preb[6] += v1.z; preb[7] += v1.w;
        }
    }
    for (int ii = 0; ii < 64; ++ii) {
        int n = ns[ii];
        float a = sa[ii], b = sb[ii];
        float g0 = 0.36787944117144233f;       // e^{-1}
        float g1 = g0 * a;
        float g2 = g1 * a * 0.5f;
        float g3 = g2 * a * (1.f / 3.f);
        float g4 = g3 * a * 0.25f;
        float g5 = g4 * a * 0.2f;
        float g6 = g5 * a * (1.f / 6.f);
        float g7 = g6 * a * (1.f / 7.f);
        float Z = a * preb[1]
                + g0 * (TB[0] - preb[0]) + g1 * (TB[1] - preb[1])
                + g2 * (TB[2] - preb[2]) + g3 * (TB[3] - preb[3])
                + g4 * (TB[4] - preb[4]) + g5 * (TB[5] - preb[5])
                + g6 * (TB[6] - preb[6]) + g7 * (TB[7] - preb[7]);
        float izv = 1.f / Z;
        float qv = qp[(size_t)n * 2048 + j];
        float ss2 = g0 * (T[0] - pre[0]) + g1 * (T[1] - pre[1])
                  + g2 * (T[2] - pre[2]) + g3 * (T[3] - pre[3])
                  + g4 * (T[4] - pre[4]) + g5 * (T[5] - pre[5])
                  + g6 * (T[6] - pre[6]) + g7 * (T[7] - pre[7]);
        float outv = (a * pre[1] + ss2) * izv + qv;
        qdifb[(size_t)n * 2048 + j] = f2b(outv);
        float bk = 1.f;
#pragma unroll
        for (int k2 = 0; k2 < 8; ++k2) { pre[k2] += bk * qv; preb[k2] += bk; bk *= b; }
    }
}

// ---------------- MFMA projection (q only): Y[r,c] = sum_k X[r,k] W[c,k] + b[c] ---------
__global__ __launch_bounds__(256) void k_projm(const float* __restrict__ X,
                                               const float* __restrict__ W,
                                               const float* __restrict__ bias,
                                               float* __restrict__ Y) {
    int tid = threadIdx.x, lane = tid & 63, wid = tid >> 6;
    int r0 = blockIdx.x * 256 + wid * 64;
    int l15 = lane & 15, kb = lane >> 4;
    f32x4 acc[4][4] = {};
#pragma unroll
    for (int kk = 0; kk < 2; ++kk) {
        short8 af[4], bf[4];
#pragma unroll
        for (int f = 0; f < 4; ++f) {
            const float* ap = X + (size_t)(r0 + f * 16 + l15) * 64 + kk * 32 + kb * 8;
            af[f] = pack8(*(const float4*)ap, *(const float4*)(ap + 4));
            const float* bp = W + (size_t)(f * 16 + l15) * 64 + kk * 32 + kb * 8;
            bf[f] = pack8(*(const float4*)bp, *(const float4*)(bp + 4));
        }
#pragma unroll
        for (int i = 0; i < 4; ++i)
#pragma unroll
            for (int j = 0; j < 4; ++j)
                acc[i][j] = MFMA16(af[i], bf[j], acc[i][j]);
    }
    float bcol[4];
#pragma unroll
    for (int j = 0; j < 4; ++j) bcol[j] = bias[j * 16 + l15];
#pragma unroll
    for (int i = 0; i < 4; ++i)
#pragma unroll
        for (int j = 0; j < 4; ++j)
#pragma unroll
            for (int r = 0; r < 4; ++r)
                Y[(size_t)(r0 + i * 16 + kb * 4 + r) * 64 + j * 16 + l15] = acc[i][j][r] + bcol[j];
}

// ---------------- WeTT[od][e] = We[e][d*64+o] bf16 (od = o*64+d) ----------------
__global__ __launch_bounds__(256) void k_wett(const float* __restrict__ We,
                                              ushort* __restrict__ WeTT) {
    int gid = blockIdx.x * 256 + threadIdx.x;   // 131072
    int od = gid >> 5, e = gid & 31;
    int o = od >> 6, d = od & 63;
    WeTT[gid] = f2b(We[(size_t)e * 4096 + d * 64 + o]);
}

// ---------------- Wn GEMM: WnT[n][od] = sum_e embbf[n][e] * WeTT[od][e] ----------------
__global__ __launch_bounds__(256) void k_wnodem(const ushort* __restrict__ embbf,
                                                const ushort* __restrict__ WeTT,
                                                ushort* __restrict__ WnT) {
    int tid = threadIdx.x, lane = tid & 63, wid = tid >> 6;
    int n0  = blockIdx.x * 128 + (wid >> 1) * 64;
    int od0 = blockIdx.y * 128 + (wid & 1) * 64;
    int l15 = lane & 15, kb = lane >> 4;
    short8 af[4], bf[4];
#pragma unroll
    for (int f = 0; f < 4; ++f) {
        af[f] = *(const short8*)(embbf + (size_t)(n0 + f * 16 + l15) * 32 + kb * 8);
        bf[f] = *(const short8*)(WeTT + (size_t)(od0 + f * 16 + l15) * 32 + kb * 8);
    }
    f32x4 acc[4][4] = {};
#pragma unroll
    for (int i = 0; i < 4; ++i)
#pragma unroll
        for (int j = 0; j < 4; ++j)
            acc[i][j] = MFMA16(af[i], bf[j], acc[i][j]);
#pragma unroll
    for (int i = 0; i < 4; ++i)
#pragma unroll
        for (int j = 0; j < 4; ++j)
#pragma unroll
            for (int r = 0; r < 4; ++r)
                WnT[(size_t)(n0 + i * 16 + kb * 4 + r) * 4096 + od0 + j * 16 + l15] =
                    f2b(acc[i][j][r]);
}

// ---------------- bnode[n,o] = sum_e emb[n,e] * be[e,o] ----------------
__global__ __launch_bounds__(256) void k_bnode(const float* __restrict__ emb,
                                               const float* __restrict__ be,
                                               float* __restrict__ bn) {
    int gid = blockIdx.x * 256 + threadIdx.x;
    int n = gid >> 6, o = gid & 63;
    float acc = 0.f;
#pragma unroll
    for (int e = 0; e < DE; ++e) acc += emb[n * DE + e] * be[e * 64 + o];
    bn[gid] = acc;
}

// ---------------- fused per-batch: MFMA proj -> MFMA attention -> MFMA epilogue ----------
__global__ __launch_bounds__(256) void k_fused(const float* __restrict__ kin,
                                               const float* __restrict__ vin,
                                               const ushort* __restrict__ qdifb,
                                               const ushort* __restrict__ WnT,
                                               const float* __restrict__ bn,
                                               const ushort* __restrict__ Wkbf,
                                               const float* __restrict__ bk,
                                               const ushort* __restrict__ Wvbf,
                                               const float* __restrict__ bv,
                                               const ushort* __restrict__ Wobf,
                                               const float* __restrict__ bo,
                                               float* __restrict__ out) {
    __shared__ ushort Kb[2048];     // [h][s][d]  8 x 32 x 8 bf16
    __shared__ ushort Qb[2048];     // [h][t][d]
    __shared__ ushort Vb[2048];     // [h][d][s]
    __shared__ ushort attb[32 * 72];// [t][d64] stride 72
    int tid = threadIdx.x, lane = tid & 63, w = tid >> 6;
    int b = blockIdx.x;
    int l15 = lane & 15, g = lane >> 4;
    int col = w * 16 + l15;

    // ---- phase 1: kp = k@Wk^T+bk, vp = v@Wv^T+bv, q2 = qdif@Wn^T+bn (wave w: cols col)
    f32x4 ck[2] = {}, cv[2] = {}, cq[2] = {};
#pragma unroll
    for (int kk = 0; kk < 2; ++kk) {
        short8 bkf = *(const short8*)(Wkbf + (size_t)col * 64 + kk * 32 + g * 8);
        short8 bvf = *(const short8*)(Wvbf + (size_t)col * 64 + kk * 32 + g * 8);
        short8 bqf = *(const short8*)(WnT + (size_t)b * 4096 + (size_t)col * 64 + kk * 32 + g * 8);
#pragma unroll
        for (int ti = 0; ti < 2; ++ti) {
            const float* ap = kin + (size_t)b * TD + (ti * 16 + l15) * 64 + kk * 32 + g * 8;
            short8 ak = pack8(*(const float4*)ap, *(const float4*)(ap + 4));
            const float* vp_ = vin + (size_t)b * TD + (ti * 16 + l15) * 64 + kk * 32 + g * 8;
            short8 av = pack8(*(const float4*)vp_, *(const float4*)(vp_ + 4));
            short8 aq = *(const short8*)(qdifb + (size_t)b * TD + (ti * 16 + l15) * 64 + kk * 32 + g * 8);
            ck[ti] = MFMA16(ak, bkf, ck[ti]);
            cv[ti] = MFMA16(av, bvf, cv[ti]);
            cq[ti] = MFMA16(aq, bqf, cq[ti]);
        }
    }
    {
        float bkc = bk[col], bvc = bv[col], bnc = bn[b * 64 + col];
        int h1 = col >> 3, d1 = col & 7;
#pragma unroll
        for (int ti = 0; ti < 2; ++ti)
#pragma unroll
            for (int r = 0; r < 4; ++r) {
                int s = ti * 16 + g * 4 + r;
                Kb[h1 * 256 + s * 8 + d1] = f2b(ck[ti][r] + bkc);
                Qb[h1 * 256 + s * 8 + d1] = f2b(cq[ti][r] + bnc);
                Vb[h1 * 256 + d1 * 32 + s] = f2b(cv[ti][r] + bvc);
            }
    }
    // wave w wrote exactly heads 2w, 2w+1 -> no barrier needed before phase 2

    // ---- phase 2: per-head MFMA attention (wave w owns heads 2w, 2w+1)
    const float SCALE = 0.35355339059327373f;   // 1/sqrt(8)
    short8 zfrag = {};
#pragma unroll
    for (int hh = 0; hh < 2; ++hh) {
        int h = w * 2 + hh;
        // S^T = K @ Q^T   (K-dim = 8, zero-padded to 32: lanes >=16 carry zeros)
        short8 kf[2], qf[2];
#pragma unroll
        for (int si = 0; si < 2; ++si)
            kf[si] = (lane < 16) ? *(const short8*)&Kb[h * 256 + (si * 16 + l15) * 8] : zfrag;
#pragma unroll
        for (int ti = 0; ti < 2; ++ti)
            qf[ti] = (lane < 16) ? *(const short8*)&Qb[h * 256 + (ti * 16 + l15) * 8] : zfrag;
        f32x4 sc[2][2];
#pragma unroll
        for (int si = 0; si < 2; ++si)
#pragma unroll
            for (int ti = 0; ti < 2; ++ti)
                sc[si][ti] = MFMA16(kf[si], qf[ti], f32x4{});
        // softmax over s for each t (t = l15 + 16*ti); lane holds s = 4g+r (+16si)
        unsigned pq[2][2][2];
#pragma unroll
        for (int ti = 0; ti < 2; ++ti) {
            float v0[4], v1[4];
#pragma unroll
            for (int r = 0; r < 4; ++r) { v0[r] = sc[0][ti][r] * SCALE; v1[r] = sc[1][ti][r] * SCALE; }
            float mx = fmaxf(fmaxf(fmaxf(v0[0], v0[1]), fmaxf(v0[2], v0[3])),
                             fmaxf(fmaxf(v1[0], v1[1]), fmaxf(v1[2], v1[3])));
            mx = fmaxf(mx, __shfl_xor(mx, 16));
            mx = fmaxf(mx, __shfl_xor(mx, 32));
            float e0[4], e1[4], sm = 0.f;
#pragma unroll
            for (int r = 0; r < 4; ++r) {
                e0[r] = __expf(v0[r] - mx); e1[r] = __expf(v1[r] - mx);
                sm += e0[r] + e1[r];
            }
            sm += __shfl_xor(sm, 16);
            sm += __shfl_xor(sm, 32);
            float inv = 1.f / sm;
            pq[0][ti][0] = (unsigned)f2b(e0[0] * inv) | ((unsigned)f2b(e0[1] * inv) << 16);
            pq[0][ti][1] = (unsigned)f2b(e0[2] * inv) | ((unsigned)f2b(e0[3] * inv) << 16);
            pq[1][ti][0] = (unsigned)f2b(e1[0] * inv) | ((unsigned)f2b(e1[1] * inv) << 16);
            pq[1][ti][1] = (unsigned)f2b(e1[2] * inv) | ((unsigned)f2b(e1[3] * inv) << 16);
        }
        // PV: relayout P (C-layout) -> A-fragment via shuffles, then MFMA with V
        short8 vf = *(const short8*)&Vb[h * 256 + (l15 & 7) * 32 + g * 8];
        int L0 = l15 + ((g & 1) << 5);
        int L1 = L0 + 16;
        bool s1 = (g >> 1) != 0;
#pragma unroll
        for (int ti = 0; ti < 2; ++ti) {
            unsigned a00 = __shfl(pq[0][ti][0], L0), a01 = __shfl(pq[0][ti][1], L0);
            unsigned a10 = __shfl(pq[1][ti][0], L0), a11 = __shfl(pq[1][ti][1], L0);
            unsigned b00 = __shfl(pq[0][ti][0], L1), b01 = __shfl(pq[0][ti][1], L1);
            unsigned b10 = __shfl(pq[1][ti][0], L1), b11 = __shfl(pq[1][ti][1], L1);
            union { unsigned u[4]; short8 s8; } af;
            af.u[0] = s1 ? a10 : a00; af.u[1] = s1 ? a11 : a01;
            af.u[2] = s1 ? b10 : b00; af.u[3] = s1 ? b11 : b01;
            f32x4 pv = MFMA16(af.s8, vf, f32x4{});
            if (l15 < 8) {
#pragma unroll
                for (int r = 0; r < 4; ++r)
                    attb[(ti * 16 + g * 4 + r) * 72 + h * 8 + l15] = f2b(pv[r]);
            }
        }
    }
    __syncthreads();

    // ---- phase 3: MFMA epilogue out = att @ Wo^T + bo (wave w: cols col)
    f32x4 co[2] = {};
#pragma unroll
    for (int kk = 0; kk < 2; ++kk) {
        short8 bof = *(const short8*)(Wobf + (size_t)col * 64 + kk * 32 + g * 8);
#pragma unroll
        for (int ti = 0; ti < 2; ++ti) {
            short8 aof = *(const short8*)&attb[(ti * 16 + l15) * 72 + kk * 32 + g * 8];
            co[ti] = MFMA16(aof, bof, co[ti]);
        }
    }
    float boc = bo[col];
#pragma unroll
    for (int ti = 0; ti < 2; ++ti)
#pragma unroll
        for (int r = 0; r < 4; ++r)
            out[(size_t)b * TD + (ti * 16 + g * 4 + r) * 64 + col] = co[ti][r] + boc;
}

extern "C" void kernel_launch(void* const* d_in, const int* in_sizes, int n_in,
                              void* d_out, int out_size, void* d_ws, size_t ws_size,
                              hipStream_t stream) {
    const float* q   = (const float*)d_in[0];
    const float* k   = (const float*)d_in[1];
    const float* v   = (const float*)d_in[2];
    const float* emb = (const float*)d_in[3];
    const float* We  = (const float*)d_in[4];
    const float* be  = (const float*)d_in[5];
    const float* Wq  = (const float*)d_in[6];
    const float* bq  = (const float*)d_in[7];
    const float* Wk  = (const float*)d_in[8];
    const float* bk  = (const float*)d_in[9];
    const float* Wv  = (const float*)d_in[10];
    const float* bv  = (const float*)d_in[11];
    const float* Wo  = (const float*)d_in[12];
    const float* bo  = (const float*)d_in[13];

    float* ws = (float*)d_ws;
    float*  qp    = ws;                                   // 32 MB
    ushort* WnT   = (ushort*)(ws + 8388608);              // 32 MB
    ushort* qdifb = (ushort*)(ws + 16777216);             // 16 MB
    float*  Cj    = ws + 20971520;                        // 4 MB
    float*  bn    = ws + 22020096;                        // 1 MB
    float*  s_g   = ws + 22282240;                        // 16 KB
    int*    perm  = (int*)(ws + 22286336);                // 16 KB
    float*  Cb    = ws + 22290432;                        // 2 KB
    ushort* embbf = (ushort*)(ws + 22290944);             // 256 KB
    ushort* WeTT  = (ushort*)(ws + 22356480);             // 256 KB
    ushort* Wkbf  = (ushort*)(ws + 22422016);             // 8 KB
    ushort* Wvbf  = (ushort*)(ws + 22424064);             // 8 KB
    ushort* Wobf  = (ushort*)(ws + 22426112);             // 8 KB
    float*  PRE   = ws + 22428160;                        // 4.25 MB (end ~94 MB)
    float*  outp  = (float*)d_out;

    k_s    <<<16, 256, 0, stream>>>(emb, s_g);
    k_rank <<<512, 256, 0, stream>>>(s_g, perm);
    k_cvt  <<<512, 256, 0, stream>>>(emb, embbf, 131072);
    k_wett <<<512, 256, 0, stream>>>(We, WeTT);
    k_cvt  <<<16, 256, 0, stream>>>(Wk, Wkbf, 4096);
    k_cvt  <<<16, 256, 0, stream>>>(Wv, Wvbf, 4096);
    k_cvt  <<<16, 256, 0, stream>>>(Wo, Wobf, 4096);
    k_projm<<<512, 256, 0, stream>>>(q, Wq, bq, qp);
    k_csum <<<dim3(64, 8), 256, 0, stream>>>(qp, s_g, perm, Cj, Cb);
    k_pre  <<<64, 256, 0, stream>>>(Cj, PRE);
    k_comb <<<dim3(64, 8), 256, 0, stream>>>(qp, s_g, perm, PRE, Cb, qdifb);
    k_wnodem<<<dim3(32, 32), 256, 0, stream>>>(embbf, WeTT, WnT);
    k_bnode<<<1024, 256, 0, stream>>>(emb, be, bn);
    k_fused<<<4096, 256, 0, stream>>>(k, v, qdifb, WnT, bn,
                                      Wkbf, bk, Wvbf, bv, Wobf, bo, outp);
}

// Round 6
// 139.284 us; speedup vs baseline: 14.4973x; 1.2185x over previous
//
#include <hip/hip_runtime.h>
#include <hip/hip_bf16.h>

constexpr int NN  = 4096;       // n_node + 1 == batch
constexpr int DE  = 32;         // d_emb
constexpr int TD  = 2048;       // T*D
constexpr int HS  = 272;        // padded head stride (ushorts) for Kb/Qb/Vb

typedef __attribute__((ext_vector_type(8))) short short8;
typedef __attribute__((ext_vector_type(4))) float f32x4;

#define MFMA16(a, b, c) __builtin_amdgcn_mfma_f32_16x16x32_bf16(a, b, c, 0, 0, 0)

__device__ inline ushort f2b(float x) {
    __hip_bfloat16 h = __float2bfloat16(x);          // RNE; compiler emits v_cvt_pk
    union { __hip_bfloat16 h; ushort u; } c; c.h = h;
    return c.u;
}

__device__ inline short8 pack8(float4 a, float4 b) {
    short8 v;
    v[0] = (short)f2b(a.x); v[1] = (short)f2b(a.y); v[2] = (short)f2b(a.z); v[3] = (short)f2b(a.w);
    v[4] = (short)f2b(b.x); v[5] = (short)f2b(b.y); v[6] = (short)f2b(b.z); v[7] = (short)f2b(b.w);
    return v;
}

// ================= k_prep: s | embbf | WeTT | W cvt x3 | bnode =================
__global__ __launch_bounds__(256) void k_prep(const float* __restrict__ emb,
                                              const float* __restrict__ We,
                                              const float* __restrict__ be,
                                              const float* __restrict__ Wk,
                                              const float* __restrict__ Wv,
                                              const float* __restrict__ Wo,
                                              float* __restrict__ s_g,
                                              ushort* __restrict__ embbf,
                                              ushort* __restrict__ WeTT,
                                              ushort* __restrict__ Wkbf,
                                              ushort* __restrict__ Wvbf,
                                              ushort* __restrict__ Wobf,
                                              float* __restrict__ bn) {
    int id = blockIdx.x, tid = threadIdx.x;
    if (id < 16) {                                   // ---- s[n]
        int n = id * 256 + tid;
        const float4* e4 = (const float4*)(emb + n * DE);
        float s = 0.f;
#pragma unroll
        for (int i = 0; i < DE / 4; ++i) { float4 v = e4[i]; s += v.x + v.y + v.z + v.w; }
        s_g[n] = s;
    } else if (id < 144) {                           // ---- embbf (vectorized)
        int g4 = (id - 16) * 256 + tid;              // 0..32767
        float4 v = *(const float4*)&emb[(size_t)g4 * 4];
        ushort4 o; o.x = f2b(v.x); o.y = f2b(v.y); o.z = f2b(v.z); o.w = f2b(v.w);
        *(ushort4*)&embbf[(size_t)g4 * 4] = o;
    } else if (id < 656) {                           // ---- WeTT[od][e] = We[e][d*64+o]
        int gid = (id - 144) * 256 + tid;            // 0..131071
        int od = gid >> 5, e = gid & 31;
        int o = od >> 6, d = od & 63;
        WeTT[gid] = f2b(We[(size_t)e * 4096 + d * 64 + o]);
    } else if (id < 704) {                           // ---- Wk/Wv/Wo bf16
        int id5 = id - 656;
        int which = id5 >> 4, gid = (id5 & 15) * 256 + tid;   // 0..4095
        const float* src = which == 0 ? Wk : (which == 1 ? Wv : Wo);
        ushort* dst = which == 0 ? Wkbf : (which == 1 ? Wvbf : Wobf);
        dst[gid] = f2b(src[gid]);
    } else {                                         // ---- bnode
        int gid = (id - 704) * 256 + tid;            // 0..262143
        int n = gid >> 6, o = gid & 63;
        float acc = 0.f;
#pragma unroll
        for (int e = 0; e < DE; ++e) acc += emb[n * DE + e] * be[e * 64 + o];
        bn[gid] = acc;
    }
}

// ================= k_pr: projm(q) [0,512) | rank [512,1024) =================
__global__ __launch_bounds__(256) void k_pr(const float* __restrict__ X,
                                            const float* __restrict__ W,
                                            const float* __restrict__ bias,
                                            float* __restrict__ Y,
                                            const float* __restrict__ s_g,
                                            int* __restrict__ perm) {
    __shared__ float ss[NN];
    int id = blockIdx.x, tid = threadIdx.x;
    if (id < 512) {
        int lane = tid & 63, wid = tid >> 6;
        int r0 = id * 256 + wid * 64;
        int l15 = lane & 15, kb = lane >> 4;
        f32x4 acc[4][4] = {};
#pragma unroll
        for (int kk = 0; kk < 2; ++kk) {
            short8 af[4], bf[4];
#pragma unroll
            for (int f = 0; f < 4; ++f) {
                const float* ap = X + (size_t)(r0 + f * 16 + l15) * 64 + kk * 32 + kb * 8;
                af[f] = pack8(*(const float4*)ap, *(const float4*)(ap + 4));
                const float* bp = W + (size_t)(f * 16 + l15) * 64 + kk * 32 + kb * 8;
                bf[f] = pack8(*(const float4*)bp, *(const float4*)(bp + 4));
            }
#pragma unroll
            for (int i = 0; i < 4; ++i)
#pragma unroll
                for (int j = 0; j < 4; ++j)
                    acc[i][j] = MFMA16(af[i], bf[j], acc[i][j]);
        }
        float bcol[4];
#pragma unroll
        for (int j = 0; j < 4; ++j) bcol[j] = bias[j * 16 + l15];
#pragma unroll
        for (int i = 0; i < 4; ++i)
#pragma unroll
            for (int j = 0; j < 4; ++j)
#pragma unroll
                for (int r = 0; r < 4; ++r)
                    Y[(size_t)(r0 + i * 16 + kb * 4 + r) * 64 + j * 16 + l15] = acc[i][j][r] + bcol[j];
    } else {
        for (int i = tid; i < NN; i += 256) ss[i] = s_g[i];
        __syncthreads();
        int g = tid >> 5, l = tid & 31;
        int n = (id - 512) * 8 + g;
        float sn = ss[n];
        int cnt = 0;
        for (int j2 = 0; j2 < 128; ++j2) {
            int m = j2 * 32 + l;
            float sm = ss[m];
            cnt += (sm < sn) || (sm == sn && m < n);
        }
        for (int off = 16; off; off >>= 1) cnt += __shfl_down(cnt, off, 32);
        if (l == 0) perm[cnt] = n;
    }
}

// ---------------- chunk sums: Cj[c][j][k] = sum_{i in chunk c} b^k * q[perm[i]][j] ------
__global__ __launch_bounds__(256) void k_csum(const float* __restrict__ qp,
                                              const float* __restrict__ s_g,
                                              const int* __restrict__ perm,
                                              float* __restrict__ Cj,
                                              float* __restrict__ Cb) {
    __shared__ int ns[64];
    __shared__ float bs[64];
    int bx = blockIdx.x, by = blockIdx.y, tid = threadIdx.x;
    if (tid < 64) {
        int n = perm[bx * 64 + tid];
        ns[tid] = n;
        bs[tid] = __expf(-s_g[n]);
    }
    __syncthreads();
    int j = by * 256 + tid;
    float run[8] = {};
    for (int ii = 0; ii < 64; ++ii) {
        float qv = qp[(size_t)ns[ii] * 2048 + j];
        float b = bs[ii], t = qv;
#pragma unroll
        for (int k2 = 0; k2 < 8; ++k2) { run[k2] += t; t *= b; }
    }
    float* cp = Cj + ((size_t)bx * 2048 + j) * 8;
    *(float4*)cp       = make_float4(run[0], run[1], run[2], run[3]);
    *(float4*)(cp + 4) = make_float4(run[4], run[5], run[6], run[7]);
    if (by == 0 && tid < 64) {
        float b = bs[tid], bk = 1.f;
#pragma unroll
        for (int k2 = 0; k2 < 8; ++k2) {
            float v = bk;
            for (int off = 32; off; off >>= 1) v += __shfl_down(v, off, 64);
            if (tid == 0) Cb[bx * 8 + k2] = v;
            bk *= b;
        }
    }
}

// ---------------- prefix over chunks ----------------
__global__ __launch_bounds__(256) void k_pre(const float* __restrict__ Cj,
                                             float* __restrict__ PRE) {
    int gid = blockIdx.x * 256 + threadIdx.x;      // 16384
    float run = 0.f;
    for (int c = 0; c < 64; ++c) {
        PRE[(size_t)c * 16384 + gid] = run;
        run += Cj[(size_t)c * 16384 + gid];
    }
    PRE[(size_t)64 * 16384 + gid] = run;
}

// ================= k_combw: comb [0,512) | wnodem [512,1536) =================
__global__ __launch_bounds__(256) void k_combw(const float* __restrict__ qp,
                                               const float* __restrict__ s_g,
                                               const int* __restrict__ perm,
                                               const float* __restrict__ PRE,
                                               const float* __restrict__ Cb,
                                               ushort* __restrict__ qdifb,
                                               const ushort* __restrict__ embbf,
                                               const ushort* __restrict__ WeTT,
                                               ushort* __restrict__ WnT) {
    __shared__ int ns[64];
    __shared__ float sa[64], sb[64];
    int id = blockIdx.x, tid = threadIdx.x;
    if (id < 512) {
        int bx = id & 63, by = id >> 6;
        if (tid < 64) {
            int n = perm[bx * 64 + tid];
            ns[tid] = n;
            float s = s_g[n];
            sa[tid] = __expf(s);
            sb[tid] = __expf(-s);
        }
        __syncthreads();
        int j = by * 256 + tid;
        float T[8], pre[8];
        {
            const float* pp = PRE + (size_t)bx * 16384 + (size_t)j * 8;
            float4 u0 = *(const float4*)pp, u1 = *(const float4*)(pp + 4);
            pre[0] = u0.x; pre[1] = u0.y; pre[2] = u0.z; pre[3] = u0.w;
            pre[4] = u1.x; pre[5] = u1.y; pre[6] = u1.z; pre[7] = u1.w;
            const float* tp = PRE + (size_t)64 * 16384 + (size_t)j * 8;
            float4 t0 = *(const float4*)tp, t1 = *(const float4*)(tp + 4);
            T[0] = t0.x; T[1] = t0.y; T[2] = t0.z; T[3] = t0.w;
            T[4] = t1.x; T[5] = t1.y; T[6] = t1.z; T[7] = t1.w;
        }
        float TB[8] = {}, preb[8] = {};
        for (int c = 0; c < 64; ++c) {
            float4 v0 = *(const float4*)&Cb[c * 8], v1 = *(const float4*)&Cb[c * 8 + 4];
            TB[0] += v0.x; TB[1] += v0.y; TB[2] += v0.z; TB[3] += v0.w;
            TB[4] += v1.x; TB[5] += v1.y; TB[6] += v1.z; TB[7] += v1.w;
            if (c < bx) {
                preb[0] += v0.x; preb[1] += v0.y; preb[2] += v0.z; preb[3] += v0.w;
                preb[4] += v1.x; preb[5] += v1.y; preb[6] += v1.z; preb[7] += v1.w;
            }
        }
        for (int ii = 0; ii < 64; ++ii) {
            int n = ns[ii];
            float a = sa[ii], b = sb[ii];
            float g0 = 0.36787944117144233f;       // e^{-1}
            float g1 = g0 * a;
            float g2 = g1 * a * 0.5f;
            float g3 = g2 * a * (1.f / 3.f);
            float g4 = g3 * a * 0.25f;
            float g5 = g4 * a * 0.2f;
            float g6 = g5 * a * (1.f / 6.f);
            float g7 = g6 * a * (1.f / 7.f);
            float Z = a * preb[1]
                    + g0 * (TB[0] - preb[0]) + g1 * (TB[1] - preb[1])
                    + g2 * (TB[2] - preb[2]) + g3 * (TB[3] - preb[3])
                    + g4 * (TB[4] - preb[4]) + g5 * (TB[5] - preb[5])
                    + g6 * (TB[6] - preb[6]) + g7 * (TB[7] - preb[7]);
            float izv = 1.f / Z;
            float qv = qp[(size_t)n * 2048 + j];
            float ss2 = g0 * (T[0] - pre[0]) + g1 * (T[1] - pre[1])
                      + g2 * (T[2] - pre[2]) + g3 * (T[3] - pre[3])
                      + g4 * (T[4] - pre[4]) + g5 * (T[5] - pre[5])
                      + g6 * (T[6] - pre[6]) + g7 * (T[7] - pre[7]);
            float outv = (a * pre[1] + ss2) * izv + qv;
            qdifb[(size_t)n * 2048 + j] = f2b(outv);
            float bk = 1.f;
#pragma unroll
            for (int k2 = 0; k2 < 8; ++k2) { pre[k2] += bk * qv; preb[k2] += bk; bk *= b; }
        }
    } else {
        int w2 = id - 512;
        int lane = tid & 63, wid = tid >> 6;
        int n0  = (w2 & 31) * 128 + (wid >> 1) * 64;
        int od0 = (w2 >> 5) * 128 + (wid & 1) * 64;
        int l15 = lane & 15, kb = lane >> 4;
        short8 af[4], bf[4];
#pragma unroll
        for (int f = 0; f < 4; ++f) {
            af[f] = *(const short8*)(embbf + (size_t)(n0 + f * 16 + l15) * 32 + kb * 8);
            bf[f] = *(const short8*)(WeTT + (size_t)(od0 + f * 16 + l15) * 32 + kb * 8);
        }
        f32x4 acc[4][4] = {};
#pragma unroll
        for (int i = 0; i < 4; ++i)
#pragma unroll
            for (int j = 0; j < 4; ++j)
                acc[i][j] = MFMA16(af[i], bf[j], acc[i][j]);
#pragma unroll
        for (int i = 0; i < 4; ++i)
#pragma unroll
            for (int j = 0; j < 4; ++j)
#pragma unroll
                for (int r = 0; r < 4; ++r)
                    WnT[(size_t)(n0 + i * 16 + kb * 4 + r) * 4096 + od0 + j * 16 + l15] =
                        f2b(acc[i][j][r]);
    }
}

// ---------------- fused per-batch: MFMA proj -> MFMA attention -> MFMA epilogue ----------
__global__ __launch_bounds__(256) void k_fused(const float* __restrict__ kin,
                                               const float* __restrict__ vin,
                                               const ushort* __restrict__ qdifb,
                                               const ushort* __restrict__ WnT,
                                               const float* __restrict__ bn,
                                               const ushort* __restrict__ Wkbf,
                                               const float* __restrict__ bk,
                                               const ushort* __restrict__ Wvbf,
                                               const float* __restrict__ bv,
                                               const ushort* __restrict__ Wobf,
                                               const float* __restrict__ bo,
                                               float* __restrict__ out) {
    __shared__ ushort Kb[8 * HS];    // [h][s][d]  pad-272 -> ~2-way conflicts
    __shared__ ushort Qb[8 * HS];    // [h][t][d]
    __shared__ ushort Vb[8 * HS];    // [h][d][s]
    __shared__ ushort attb[32 * 72]; // [t][d64] stride 72
    int tid = threadIdx.x, lane = tid & 63, w = tid >> 6;
    int b = blockIdx.x;
    int l15 = lane & 15, g = lane >> 4;
    int col = w * 16 + l15;

    // ---- phase 1: kp = k@Wk^T+bk, vp = v@Wv^T+bv, q2 = qdif@Wn^T+bn (wave w: cols col)
    f32x4 ck[2] = {}, cv[2] = {}, cq[2] = {};
#pragma unroll
    for (int kk = 0; kk < 2; ++kk) {
        short8 bkf = *(const short8*)(Wkbf + (size_t)col * 64 + kk * 32 + g * 8);
        short8 bvf = *(const short8*)(Wvbf + (size_t)col * 64 + kk * 32 + g * 8);
        short8 bqf = *(const short8*)(WnT + (size_t)b * 4096 + (size_t)col * 64 + kk * 32 + g * 8);
#pragma unroll
        for (int ti = 0; ti < 2; ++ti) {
            const float* ap = kin + (size_t)b * TD + (ti * 16 + l15) * 64 + kk * 32 + g * 8;
            short8 ak = pack8(*(const float4*)ap, *(const float4*)(ap + 4));
            const float* vp_ = vin + (size_t)b * TD + (ti * 16 + l15) * 64 + kk * 32 + g * 8;
            short8 av = pack8(*(const float4*)vp_, *(const float4*)(vp_ + 4));
            short8 aq = *(const short8*)(qdifb + (size_t)b * TD + (ti * 16 + l15) * 64 + kk * 32 + g * 8);
            ck[ti] = MFMA16(ak, bkf, ck[ti]);
            cv[ti] = MFMA16(av, bvf, cv[ti]);
            cq[ti] = MFMA16(aq, bqf, cq[ti]);
        }
    }
    {
        float bkc = bk[col], bvc = bv[col], bnc = bn[b * 64 + col];
        int h1 = col >> 3, d1 = col & 7;
#pragma unroll
        for (int ti = 0; ti < 2; ++ti) {
#pragma unroll
            for (int r = 0; r < 4; ++r) {
                int s = ti * 16 + g * 4 + r;
                Kb[h1 * HS + s * 8 + d1] = f2b(ck[ti][r] + bkc);
                Qb[h1 * HS + s * 8 + d1] = f2b(cq[ti][r] + bnc);
            }
#pragma unroll
            for (int r = 0; r < 4; r += 2) {          // packed b32 V writes
                int s = ti * 16 + g * 4 + r;
                ushort2 p; p.x = f2b(cv[ti][r] + bvc); p.y = f2b(cv[ti][r + 1] + bvc);
                *(ushort2*)&Vb[h1 * HS + d1 * 32 + s] = p;
            }
        }
    }
    // wave w wrote exactly heads 2w, 2w+1 -> no barrier needed before phase 2

    // ---- phase 2: per-head MFMA attention (wave w owns heads 2w, 2w+1)
    const float SCALE = 0.35355339059327373f;   // 1/sqrt(8)
    short8 zfrag = {};
#pragma unroll
    for (int hh = 0; hh < 2; ++hh) {
        int h = w * 2 + hh;
        // S^T = K @ Q^T   (K-dim = 8, zero-padded to 32: lanes >=16 carry zeros)
        short8 kf[2], qf[2];
#pragma unroll
        for (int si = 0; si < 2; ++si)
            kf[si] = (lane < 16) ? *(const short8*)&Kb[h * HS + (si * 16 + l15) * 8] : zfrag;
#pragma unroll
        for (int ti = 0; ti < 2; ++ti)
            qf[ti] = (lane < 16) ? *(const short8*)&Qb[h * HS + (ti * 16 + l15) * 8] : zfrag;
        f32x4 sc[2][2];
#pragma unroll
        for (int si = 0; si < 2; ++si)
#pragma unroll
            for (int ti = 0; ti < 2; ++ti)
                sc[si][ti] = MFMA16(kf[si], qf[ti], f32x4{});
        // softmax over s (no max-sub: |scores| < ~2 by construction)
        unsigned pq[2][2][2];
#pragma unroll
        for (int ti = 0; ti < 2; ++ti) {
            float e0[4], e1[4], sm = 0.f;
#pragma unroll
            for (int r = 0; r < 4; ++r) {
                e0[r] = __expf(sc[0][ti][r] * SCALE);
                e1[r] = __expf(sc[1][ti][r] * SCALE);
                sm += e0[r] + e1[r];
            }
            sm += __shfl_xor(sm, 16);
            sm += __shfl_xor(sm, 32);
            float inv = 1.f / sm;
            pq[0][ti][0] = (unsigned)f2b(e0[0] * inv) | ((unsigned)f2b(e0[1] * inv) << 16);
            pq[0][ti][1] = (unsigned)f2b(e0[2] * inv) | ((unsigned)f2b(e0[3] * inv) << 16);
            pq[1][ti][0] = (unsigned)f2b(e1[0] * inv) | ((unsigned)f2b(e1[1] * inv) << 16);
            pq[1][ti][1] = (unsigned)f2b(e1[2] * inv) | ((unsigned)f2b(e1[3] * inv) << 16);
        }
        // PV: relayout P (C-layout) -> A-fragment via shuffles, then MFMA with V
        short8 vf = *(const short8*)&Vb[h * HS + (l15 & 7) * 32 + g * 8];
        int L0 = l15 + ((g & 1) << 5);
        int L1 = L0 + 16;
        bool s1 = (g >> 1) != 0;
#pragma unroll
        for (int ti = 0; ti < 2; ++ti) {
            unsigned a00 = __shfl(pq[0][ti][0], L0), a01 = __shfl(pq[0][ti][1], L0);
            unsigned a10 = __shfl(pq[1][ti][0], L0), a11 = __shfl(pq[1][ti][1], L0);
            unsigned b00 = __shfl(pq[0][ti][0], L1), b01 = __shfl(pq[0][ti][1], L1);
            unsigned b10 = __shfl(pq[1][ti][0], L1), b11 = __shfl(pq[1][ti][1], L1);
            union { unsigned u[4]; short8 s8; } af;
            af.u[0] = s1 ? a10 : a00; af.u[1] = s1 ? a11 : a01;
            af.u[2] = s1 ? b10 : b00; af.u[3] = s1 ? b11 : b01;
            f32x4 pv = MFMA16(af.s8, vf, f32x4{});
            if (l15 < 8) {
#pragma unroll
                for (int r = 0; r < 4; ++r)
                    attb[(ti * 16 + g * 4 + r) * 72 + h * 8 + l15] = f2b(pv[r]);
            }
        }
    }
    __syncthreads();

    // ---- phase 3: MFMA epilogue out = att @ Wo^T + bo (wave w: cols col)
    f32x4 co[2] = {};
#pragma unroll
    for (int kk = 0; kk < 2; ++kk) {
        short8 bof = *(const short8*)(Wobf + (size_t)col * 64 + kk * 32 + g * 8);
#pragma unroll
        for (int ti = 0; ti < 2; ++ti) {
            short8 aof = *(const short8*)&attb[(ti * 16 + l15) * 72 + kk * 32 + g * 8];
            co[ti] = MFMA16(aof, bof, co[ti]);
        }
    }
    float boc = bo[col];
#pragma unroll
    for (int ti = 0; ti < 2; ++ti)
#pragma unroll
        for (int r = 0; r < 4; ++r)
            out[(size_t)b * TD + (ti * 16 + g * 4 + r) * 64 + col] = co[ti][r] + boc;
}

extern "C" void kernel_launch(void* const* d_in, const int* in_sizes, int n_in,
                              void* d_out, int out_size, void* d_ws, size_t ws_size,
                              hipStream_t stream) {
    const float* q   = (const float*)d_in[0];
    const float* k   = (const float*)d_in[1];
    const float* v   = (const float*)d_in[2];
    const float* emb = (const float*)d_in[3];
    const float* We  = (const float*)d_in[4];
    const float* be  = (const float*)d_in[5];
    const float* Wq  = (const float*)d_in[6];
    const float* bq  = (const float*)d_in[7];
    const float* Wk  = (const float*)d_in[8];
    const float* bk  = (const float*)d_in[9];
    const float* Wv  = (const float*)d_in[10];
    const float* bv  = (const float*)d_in[11];
    const float* Wo  = (const float*)d_in[12];
    const float* bo  = (const float*)d_in[13];

    float* ws = (float*)d_ws;
    float*  qp    = ws;                                   // 32 MB
    ushort* WnT   = (ushort*)(ws + 8388608);              // 32 MB
    ushort* qdifb = (ushort*)(ws + 16777216);             // 16 MB
    float*  Cj    = ws + 20971520;                        // 4 MB
    float*  bn    = ws + 22020096;                        // 1 MB
    float*  s_g   = ws + 22282240;                        // 16 KB
    int*    perm  = (int*)(ws + 22286336);                // 16 KB
    float*  Cb    = ws + 22290432;                        // 2 KB
    ushort* embbf = (ushort*)(ws + 22290944);             // 256 KB
    ushort* WeTT  = (ushort*)(ws + 22356480);             // 256 KB
    ushort* Wkbf  = (ushort*)(ws + 22422016);             // 8 KB
    ushort* Wvbf  = (ushort*)(ws + 22424064);             // 8 KB
    ushort* Wobf  = (ushort*)(ws + 22426112);             // 8 KB
    float*  PRE   = ws + 22428160;                        // 4.25 MB (end ~94 MB)
    float*  outp  = (float*)d_out;

    k_prep <<<1728, 256, 0, stream>>>(emb, We, be, Wk, Wv, Wo,
                                      s_g, embbf, WeTT, Wkbf, Wvbf, Wobf, bn);
    k_pr   <<<1024, 256, 0, stream>>>(q, Wq, bq, qp, s_g, perm);
    k_csum <<<dim3(64, 8), 256, 0, stream>>>(qp, s_g, perm, Cj, Cb);
    k_pre  <<<64, 256, 0, stream>>>(Cj, PRE);
    k_combw<<<1536, 256, 0, stream>>>(qp, s_g, perm, PRE, Cb, qdifb,
                                      embbf, WeTT, WnT);
    k_fused<<<4096, 256, 0, stream>>>(k, v, qdifb, WnT, bn,
                                      Wkbf, bk, Wvbf, bv, Wobf, bo, outp);
}